// Round 12
// baseline (382.210 us; speedup 1.0000x reference)
//
#include <hip/hip_runtime.h>
#include <hip/hip_bf16.h>
#include <math.h>

#define F_     8
#define DIM_   1920
#define HEADS_ 30
#define HD_    64
#define RANK_  128
#define T_     226
#define SV_    2048
#define S_     2274
#define SP_    2304   // S_ padded to 64-key tiles (V^T leading-dim)

#define BM 128
#define BN 128
#define BK 32

using short8  = __attribute__((ext_vector_type(8))) short;
using f32x4   = __attribute__((ext_vector_type(4))) float;
using i32x4v  = __attribute__((ext_vector_type(4))) int;
using ushort4v= __attribute__((ext_vector_type(4))) unsigned short;

__device__ __forceinline__ unsigned short f2b(float f) {
  unsigned int u = __float_as_uint(f);
  u = (u + 0x7FFFu + ((u >> 16) & 1u)) >> 16;
  return (unsigned short)u;
}
__device__ __forceinline__ float b2f(unsigned short s) {
  return __uint_as_float(((unsigned int)s) << 16);
}
__device__ __forceinline__ void gload_lds16(const void* g, void* l) {
  __builtin_amdgcn_global_load_lds(
      (const __attribute__((address_space(1))) unsigned int*)g,
      (__attribute__((address_space(3))) unsigned int*)l, 16, 0, 0);
}
// bijective XCD-aware swizzle (m204)
__device__ __forceinline__ void xcd_swz(int& bx, int& by) {
  const int nx = gridDim.x;
  const int nwg = nx * gridDim.y;
  const int lid = by * nx + bx;
  const int q = nwg >> 3, r = nwg & 7;
  const int xcd = lid & 7, pos = lid >> 3;
  const int wg = (xcd < r ? xcd * (q + 1) : r * (q + 1) + (xcd - r) * q) + pos;
  bx = wg % nx; by = wg / nx;
}

// ============================================================================
// MFMA bf16 GEMM:  C(MxN) = A(MxK) @ B(NxK)^T [+ bias]
// AMODE 0: plain A; 1: conv shifts; 2: concat rows; 3: conv1 split-K x12
// OUTMODE 0: f32  1: bf16  2: f32 tuple-remap
//         3: bf16 QKV col-split; V (cols >= 2*DIM_) written TRANSPOSED to VT
// ============================================================================
template<int AMODE, int OUTMODE>
__global__ __launch_bounds__(256) void gemm_mfma(
    const unsigned short* __restrict__ A,
    const unsigned short* __restrict__ A2,
    const unsigned short* __restrict__ B,
    const float* __restrict__ bias,
    void* __restrict__ Cout,
    unsigned short* __restrict__ VT,
    int M, int N, int K, int lda, int ldb, int kinner)
{
  __shared__ __align__(16) unsigned short As[BM * BK];
  __shared__ __align__(16) unsigned short Bs[BN * BK];
  if constexpr (AMODE == 3) {
    const int z = blockIdx.z;
    A += (size_t)z * 480;
    B += (size_t)(z >> 2) * 256 * DIM_ + (z & 3) * 480;
    Cout = (void*)((float*)Cout + (size_t)z * M * N);
  }
  int bx = blockIdx.x, by = blockIdx.y;
  xcd_swz(bx, by);
  const int t   = threadIdx.x;
  const int w   = t >> 6, l = t & 63;
  const int wr  = w >> 1, wc = w & 1;
  const int row0 = by * BM, col0 = bx * BN;
  const int lr  = l & 15;
  const int lcg = l >> 4;
  const int sel = (lr >> 1) & 3;
  const int sr  = t >> 2;
  const int sc  = t & 3;

  f32x4 acc[4][4];
#pragma unroll
  for (int i = 0; i < 4; ++i)
#pragma unroll
    for (int j = 0; j < 4; ++j) acc[i][j] = (f32x4){0.f, 0.f, 0.f, 0.f};

  for (int k0 = 0; k0 < K; k0 += BK) {
    int kseg = 0, kcol = k0;
    if constexpr (AMODE == 1) { kseg = k0 / kinner; kcol = k0 - kseg * kinner; }
#pragma unroll
    for (int it = 0; it < 2; ++it) {
      const int r    = it * 64 + sr;
      const int csrc = sc ^ ((r >> 1) & 3);
      int ar = row0 + r; if (ar > M - 1) ar = M - 1;
      const unsigned short* asrc;
      if constexpr (AMODE == 1) {
        asrc = A + (size_t)(ar + kseg * 256) * kinner + kcol + csrc * 8;
      } else if constexpr (AMODE == 2) {
        asrc = (ar < T_) ? (A  + (size_t)ar        * DIM_ + k0 + csrc * 8)
                         : (A2 + (size_t)(ar - T_) * DIM_ + k0 + csrc * 8);
      } else {
        asrc = A + (size_t)ar * lda + k0 + csrc * 8;
      }
      gload_lds16(asrc, (char*)As + it * 4096 + t * 16);
      const unsigned short* bsrc = B + (size_t)(col0 + r) * ldb + k0 + csrc * 8;
      gload_lds16(bsrc, (char*)Bs + it * 4096 + t * 16);
    }
    __syncthreads();

    short8 af[4], bfv[4];
#pragma unroll
    for (int m = 0; m < 4; ++m) {
      int r = wr * 64 + m * 16 + lr;
      af[m] = *(const short8*)((const char*)As + r * 64 + ((lcg ^ sel) << 4));
    }
#pragma unroll
    for (int n = 0; n < 4; ++n) {
      int r = wc * 64 + n * 16 + lr;
      bfv[n] = *(const short8*)((const char*)Bs + r * 64 + ((lcg ^ sel) << 4));
    }
    __builtin_amdgcn_s_setprio(1);
#pragma unroll
    for (int m = 0; m < 4; ++m)
#pragma unroll
      for (int n = 0; n < 4; ++n)
        acc[m][n] = __builtin_amdgcn_mfma_f32_16x16x32_bf16(af[m], bfv[n], acc[m][n], 0, 0, 0);
    __builtin_amdgcn_s_setprio(0);
    __syncthreads();
  }

#pragma unroll
  for (int m = 0; m < 4; ++m) {
    const int rbase = row0 + wr * 64 + m * 16 + lcg * 4;
#pragma unroll
    for (int n = 0; n < 4; ++n) {
      const int c = col0 + wc * 64 + n * 16 + lr;
      const float bi = bias ? bias[c] : 0.f;
      if constexpr (OUTMODE == 3) {
        const int buf = c / DIM_, cc = c - buf * DIM_;
        if (buf == 2) {
          // V^T: [d=cc][key=r], 4 consecutive keys -> one 8B store
          unsigned short* vt = VT + (size_t)cc * SP_ + rbase;
          if (rbase + 4 <= M) {
            ushort4v o = {f2b(acc[m][n][0] + bi), f2b(acc[m][n][1] + bi),
                          f2b(acc[m][n][2] + bi), f2b(acc[m][n][3] + bi)};
            *(ushort4v*)vt = o;
          } else {
#pragma unroll
            for (int reg = 0; reg < 4; ++reg)
              if (rbase + reg < M) vt[reg] = f2b(acc[m][n][reg] + bi);
          }
        } else {
#pragma unroll
          for (int reg = 0; reg < 4; ++reg) {
            const int r = rbase + reg;
            if (r < M)
              ((unsigned short*)Cout)[(size_t)buf * S_ * DIM_ + (size_t)r * DIM_ + cc]
                  = f2b(acc[m][n][reg] + bi);
          }
        }
      } else {
#pragma unroll
        for (int reg = 0; reg < 4; ++reg) {
          const int r = rbase + reg;
          if (r >= M) continue;
          const float v = acc[m][n][reg] + bi;
          if constexpr (OUTMODE == 0) {
            ((float*)Cout)[(size_t)r * N + c] = v;
          } else if constexpr (OUTMODE == 1) {
            ((unsigned short*)Cout)[(size_t)r * N + c] = f2b(v);
          } else {
            const size_t orow = (r >= T_) ? (size_t)(r - T_) : (size_t)(SV_ + r);
            ((float*)Cout)[orow * N + c] = v;
          }
        }
      }
    }
  }
}

// P-fragment exchange: 8 bpermutes -> one A-frag (verified mapping)
__device__ __forceinline__ short8 build_pa(int c0lo, int c0hi, int c1lo, int c1hi,
                                           int addrA, bool hi_m) {
  const int a0 = __builtin_amdgcn_ds_bpermute(addrA,      c0lo);
  const int b0 = __builtin_amdgcn_ds_bpermute(addrA,      c1lo);
  const int a1 = __builtin_amdgcn_ds_bpermute(addrA,      c0hi);
  const int b1 = __builtin_amdgcn_ds_bpermute(addrA,      c1hi);
  const int a2 = __builtin_amdgcn_ds_bpermute(addrA + 64, c0lo);
  const int b2 = __builtin_amdgcn_ds_bpermute(addrA + 64, c1lo);
  const int a3 = __builtin_amdgcn_ds_bpermute(addrA + 64, c0hi);
  const int b3 = __builtin_amdgcn_ds_bpermute(addrA + 64, c1hi);
  i32x4v pw;
  pw[0] = hi_m ? b0 : a0;
  pw[1] = hi_m ? b1 : a1;
  pw[2] = hi_m ? b2 : a2;
  pw[3] = hi_m ? b3 : a3;
  return __builtin_bit_cast(short8, pw);
}

// ============================================================================
// MFMA flash attention, split-S x2, QBLK=64.
// BOTH K and V^T staged in LDS via global_load_lds (dbuf, pre-swizzled src) —
// single vmcnt/DMA queue, drained once per tile at the barrier.
// No ds_write, no reg round-trip. LDS = 32 KB.
// Writes UNNORMALIZED O-partial (bf16) + per-(q,h) {m,l} (f32) for LSE merge.
// ============================================================================
__global__ __launch_bounds__(256) void attn_mfma(
    const unsigned short* __restrict__ Qbb,
    const unsigned short* __restrict__ Kbb,
    const unsigned short* __restrict__ VT,
    unsigned short* __restrict__ Op0,
    unsigned short* __restrict__ Op1,
    float* __restrict__ ml)
{
  __shared__ __align__(16) unsigned short Kl[2][64 * 64];   // [key][d], swz 16B
  __shared__ __align__(16) unsigned short Vl[2][64 * 64];   // [d][key], swz 16B

  const int sv = blockIdx.z;
  int bx = blockIdx.x, by = blockIdx.y;
  xcd_swz(bx, by);
  const int qb = bx, h = by;
  const int t = threadIdx.x, w = t >> 6, l = t & 63;
  const int lr = l & 15, lg = l >> 4;
  const int q0 = qb * 64;
  const int j0base = sv * 1152;
  const int NT = 18;
  unsigned short* Opart = sv ? Op1 : Op0;

  short8 qa[2];
  {
    int qrow = q0 + w * 16 + lr; if (qrow >= S_) qrow = S_ - 1;
    const unsigned short* qp = Qbb + (size_t)qrow * DIM_ + h * 64 + lg * 8;
    qa[0] = *(const short8*)qp;
    qa[1] = *(const short8*)(qp + 32);
  }

  // staging constants: row within 64-row tile, pre-swizzled col (involution)
  const int srow = t >> 3;                 // +32 for second half
  const int sc0 = ((((t & 7) * 16) ^ ((srow        & 7) << 4)) >> 1);  // ushorts
  const int sc1 = ((((t & 7) * 16) ^ (((srow + 32) & 7) << 4)) >> 1);
  // V^T source rows for this thread (d rows are always valid)
  const unsigned short* vsrc0 = VT + (size_t)(h * 64 + srow)      * SP_ + sc0;
  const unsigned short* vsrc1 = VT + (size_t)(h * 64 + srow + 32) * SP_ + sc1;

  f32x4 oacc[4];
#pragma unroll
  for (int n = 0; n < 4; ++n) oacc[n] = (f32x4){0.f, 0.f, 0.f, 0.f};
  float m_run = -1e30f, l_run = 0.f;

  const int addrA = (lr + ((lg & 1) << 5)) << 2;
  const bool hi_m = (lg & 2) != 0;

  // ---- prologue: stage K+V tile 0 of this half ----
  {
    int k0 = j0base + srow;      if (k0 >= S_) k0 = S_ - 1;
    int k1 = j0base + srow + 32; if (k1 >= S_) k1 = S_ - 1;
    gload_lds16(Kbb + (size_t)k0 * DIM_ + h * 64 + sc0, (char*)Kl[0] + t * 16);
    gload_lds16(Kbb + (size_t)k1 * DIM_ + h * 64 + sc1, (char*)Kl[0] + 4096 + t * 16);
    gload_lds16(vsrc0 + j0base, (char*)Vl[0] + t * 16);
    gload_lds16(vsrc1 + j0base, (char*)Vl[0] + 4096 + t * 16);
  }
  __syncthreads();

  for (int jt = 0; jt < NT; ++jt) {
    const int j0 = j0base + jt * 64;
    const int cur = jt & 1;

    // ---- issue K+V prefetch for next tile (clamped re-read on last iter) --
    const int jn0 = (jt + 1 < NT) ? j0 + 64 : j0;
    {
      int k0 = jn0 + srow;      if (k0 >= S_) k0 = S_ - 1;
      int k1 = jn0 + srow + 32; if (k1 >= S_) k1 = S_ - 1;
      gload_lds16(Kbb + (size_t)k0 * DIM_ + h * 64 + sc0,
                  (char*)Kl[cur ^ 1] + t * 16);
      gload_lds16(Kbb + (size_t)k1 * DIM_ + h * 64 + sc1,
                  (char*)Kl[cur ^ 1] + 4096 + t * 16);
      gload_lds16(vsrc0 + jn0, (char*)Vl[cur ^ 1] + t * 16);
      gload_lds16(vsrc1 + jn0, (char*)Vl[cur ^ 1] + 4096 + t * 16);
    }

    // ---- S^T = K @ Q^T : lane holds S[key = m*16+lg*4+r][q = lr] ----
    f32x4 sacc[4];
#pragma unroll
    for (int m = 0; m < 4; ++m) sacc[m] = (f32x4){0.f, 0.f, 0.f, 0.f};
    __builtin_amdgcn_s_setprio(1);
#pragma unroll
    for (int m = 0; m < 4; ++m) {
#pragma unroll
      for (int ks = 0; ks < 2; ++ks) {
        const short8 kb = *(const short8*)((const char*)Kl[cur] + (m * 16 + lr) * 128 +
                              ((ks * 64 + lg * 16) ^ ((lr & 7) << 4)));
        sacc[m] = __builtin_amdgcn_mfma_f32_16x16x32_bf16(kb, qa[ks], sacc[m], 0, 0, 0);
      }
    }
    __builtin_amdgcn_s_setprio(0);

    if (j0 + 64 > S_) {
#pragma unroll
      for (int m = 0; m < 4; ++m)
#pragma unroll
        for (int r = 0; r < 4; ++r)
          if (j0 + m * 16 + lg * 4 + r >= S_) sacc[m][r] = -1e30f;
    }

    // ---- row max ----
    float mx = sacc[0][0];
#pragma unroll
    for (int m = 0; m < 4; ++m)
#pragma unroll
      for (int r = 0; r < 4; ++r) mx = fmaxf(mx, sacc[m][r]);
    mx = fmaxf(mx, __shfl_xor(mx, 16));
    mx = fmaxf(mx, __shfl_xor(mx, 32));

    // ---- defer-max rescale (exp2 domain, THR=8) ----
    if (!__all(mx <= m_run + 8.0f)) {
      const float mnew = fmaxf(m_run, mx);
      const float sc = exp2f(m_run - mnew);
      l_run *= sc;
      float scr[4];
#pragma unroll
      for (int r = 0; r < 4; ++r) scr[r] = __shfl(sc, (l & 48) | (lg * 4 + r));
#pragma unroll
      for (int n = 0; n < 4; ++n)
#pragma unroll
        for (int r = 0; r < 4; ++r) oacc[n][r] *= scr[r];
      m_run = mnew;
    }

    // ---- P = exp2(S - m), packed to bf16 pairs in-register ----
    float rs = 0.f;
    int c[4][2];
#pragma unroll
    for (int m = 0; m < 4; ++m) {
      const float p0 = exp2f(sacc[m][0] - m_run);
      const float p1 = exp2f(sacc[m][1] - m_run);
      const float p2 = exp2f(sacc[m][2] - m_run);
      const float p3 = exp2f(sacc[m][3] - m_run);
      rs += (p0 + p1) + (p2 + p3);
      asm("v_cvt_pk_bf16_f32 %0, %1, %2" : "=v"(c[m][0]) : "v"(p0), "v"(p1));
      asm("v_cvt_pk_bf16_f32 %0, %1, %2" : "=v"(c[m][1]) : "v"(p2), "v"(p3));
    }
    rs += __shfl_xor(rs, 16);
    rs += __shfl_xor(rs, 32);
    l_run += rs;

    // ---- P A-frags via bpermute, then O += P @ V (V^T from LDS) ----
    __builtin_amdgcn_s_setprio(1);
    {
      const short8 pa0 = build_pa(c[0][0], c[0][1], c[1][0], c[1][1], addrA, hi_m);
#pragma unroll
      for (int n = 0; n < 4; ++n) {
        const short8 vb = *(const short8*)((const char*)Vl[cur] + (n * 16 + lr) * 128 +
                              ((0 * 64 + lg * 16) ^ ((lr & 7) << 4)));
        oacc[n] = __builtin_amdgcn_mfma_f32_16x16x32_bf16(pa0, vb, oacc[n], 0, 0, 0);
      }
      const short8 pa1 = build_pa(c[2][0], c[2][1], c[3][0], c[3][1], addrA, hi_m);
#pragma unroll
      for (int n = 0; n < 4; ++n) {
        const short8 vb = *(const short8*)((const char*)Vl[cur] + (n * 16 + lr) * 128 +
                              ((1 * 64 + lg * 16) ^ ((lr & 7) << 4)));
        oacc[n] = __builtin_amdgcn_mfma_f32_16x16x32_bf16(pa1, vb, oacc[n], 0, 0, 0);
      }
    }
    __builtin_amdgcn_s_setprio(0);

    __syncthreads();     // drains K+V DMA; Kl/Vl[cur^1] ready for next iter
  }

  // ---- epilogue: store UNNORMALIZED partial + {m,l} ----
#pragma unroll
  for (int r = 0; r < 4; ++r) {
    const int row = q0 + w * 16 + lg * 4 + r;
    if (row >= S_) continue;
#pragma unroll
    for (int n = 0; n < 4; ++n)
      Opart[(size_t)row * DIM_ + h * 64 + n * 16 + lr] = f2b(oacc[n][r]);
  }
  if (l < 16) {                       // lg==0 lane holds (m,l) for q = lr
    const int row = q0 + w * 16 + lr;
    if (row < S_) {
      float2 v; v.x = m_run; v.y = l_run;
      *(float2*)(ml + ((size_t)(sv * S_ + row) * HEADS_ + h) * 2) = v;
    }
  }
}

// ============================================================================
// merge split-S partials (LSE combine) + conv-branch add -> bf16
// fused tail range: out-proj weight f32 -> bf16 (x8 vectorized)
// ============================================================================
#define MERGE_N_ (S_ * DIM_ / 8)
#define CVT_N_   (DIM_ * DIM_ / 8)
__global__ void merge_k(const unsigned short* __restrict__ Op0,
                        const unsigned short* __restrict__ Op1,
                        const float* __restrict__ ml,
                        const unsigned short* __restrict__ y2b,
                        unsigned short* __restrict__ dst,
                        const float* __restrict__ ow,
                        unsigned short* __restrict__ owb)
{
  const int i = blockIdx.x * 256 + threadIdx.x;
  if (i < MERGE_N_) {
    const int e = i * 8;
    const int row = e / DIM_, col = e % DIM_;
    const int h = col >> 6;
    const float* p0 = ml + ((size_t)row * HEADS_ + h) * 2;
    const float* p1 = ml + ((size_t)(S_ + row) * HEADS_ + h) * 2;
    const float m0 = p0[0], l0 = p0[1], m1 = p1[0], l1 = p1[1];
    const float M = fmaxf(m0, m1);
    const float w0 = exp2f(m0 - M), w1 = exp2f(m1 - M);
    const float inv = 1.f / (w0 * l0 + w1 * l1);
    const short8 a = *(const short8*)(Op0 + e);
    const short8 b = *(const short8*)(Op1 + e);
    const bool cadd = row >= T_;
    const unsigned short* yp = y2b + (size_t)(row - T_) * DIM_ + col;
    short8 o;
#pragma unroll
    for (int j = 0; j < 8; ++j) {
      float v = (w0 * b2f((unsigned short)a[j]) + w1 * b2f((unsigned short)b[j])) * inv;
      if (cadd) v += b2f(yp[j]);
      o[j] = (short)f2b(v);
    }
    *(short8*)(dst + e) = o;
  } else if (i < MERGE_N_ + CVT_N_) {
    const int e = (i - MERGE_N_) * 8;
    const float4 v0 = *(const float4*)(ow + e);
    const float4 v1 = *(const float4*)(ow + e + 4);
    short8 o;
    o[0]=(short)f2b(v0.x); o[1]=(short)f2b(v0.y); o[2]=(short)f2b(v0.z); o[3]=(short)f2b(v0.w);
    o[4]=(short)f2b(v1.x); o[5]=(short)f2b(v1.y); o[6]=(short)f2b(v1.z); o[7]=(short)f2b(v1.w);
    *(short8*)(owb + e) = o;
  }
}

// ============================================================================
// fused input conversions (one launch)
// ============================================================================
#define U0_ 1228800
#define U1_ 3993600
#define U2_ 4427520
#define U3_ 5164800
#define U4_ 5902080
#define U5_ 5907840
__global__ void prep_all(const float* __restrict__ hid, const float* __restrict__ enc,
                         const float* __restrict__ w1, const float* __restrict__ w2,
                         const float* __restrict__ qw, const float* __restrict__ kw,
                         const float* __restrict__ vw, const float* __restrict__ qb2,
                         const float* __restrict__ kb2, const float* __restrict__ vb2,
                         unsigned short* __restrict__ hidpad, unsigned short* __restrict__ encb,
                         unsigned short* __restrict__ w1p, unsigned short* __restrict__ w2p,
                         unsigned short* __restrict__ wqkv, float* __restrict__ bqkv)
{
  const int i = blockIdx.x * 256 + threadIdx.x;
  if (i < U0_) {                                   // hidpad (zero-padded), x4
    const int e = i * 4;
    const int r = e / DIM_;
    ushort4v o = (ushort4v){0, 0, 0, 0};
    if (r >= 256 && r < 256 + SV_) {
      const float4 v = *(const float4*)(hid + e - 256 * DIM_);
      o[0] = f2b(v.x); o[1] = f2b(v.y); o[2] = f2b(v.z); o[3] = f2b(v.w);
    }
    *(ushort4v*)(hidpad + e) = o;
  } else if (i < U1_) {                            // fused QKV weights, x4
    const int e = (i - U0_) * 4;
    const int which = e / (DIM_ * DIM_);
    const int j = e - which * DIM_ * DIM_;
    const float* s = which == 0 ? qw : which == 1 ? kw : vw;
    const float4 v = *(const float4*)(s + j);
    ushort4v o = {f2b(v.x), f2b(v.y), f2b(v.z), f2b(v.w)};
    *(ushort4v*)(wqkv + e) = o;
  } else if (i < U2_) {                            // encoder bf16
    const int e = i - U1_;
    encb[e] = f2b(enc[e]);
  } else if (i < U3_) {                            // conv1 w permute
    const int e = i - U2_;
    const int oc = e / (DIM_ * 3), rem = e % (DIM_ * 3);
    const int ks = rem / DIM_, ic = rem % DIM_;
    w1p[e] = f2b(w1[(size_t)oc * DIM_ * 3 + ic * 3 + ks]);
  } else if (i < U4_) {                            // conv2 w permute
    const int e = i - U3_;
    const int oc = e / (RANK_ * 3), rem = e % (RANK_ * 3);
    const int ks = rem / RANK_, rc = rem % RANK_;
    w2p[e] = f2b(w2[(size_t)oc * RANK_ * 3 + rc * 3 + ks]);
  } else if (i < U5_) {                            // fused QKV bias (f32)
    const int e = i - U4_;
    const int which = e / DIM_, j = e % DIM_;
    bqkv[e] = which == 0 ? qb2[j] : which == 1 ? kb2[j] : vb2[j];
  }
}

// sum 12 split-K partials of y1^T [128][2048], GELU, write padded [2560][128]
__global__ void gelupad_k(const float* __restrict__ y1T, unsigned short* __restrict__ dst)
{
  int i = blockIdx.x * 256 + threadIdx.x;
  if (i >= 2560 * RANK_) return;
  int r = i / RANK_, rc = i % RANK_;
  unsigned short o = 0;
  if (r >= 256 && r < 256 + SV_) {
    int s = r - 256;
    float x = 0.f;
#pragma unroll
    for (int z = 0; z < 12; ++z)
      x += y1T[(size_t)z * RANK_ * SV_ + (size_t)rc * SV_ + s];
    o = f2b(0.5f * x * (1.f + erff(x * 0.70710678118654752f)));
  }
  dst[i] = o;
}

// LN over HD=64 + RoPE, bf16 in place; Q branch scaled by log2(e)/8
__global__ __launch_bounds__(256) void qknorm_rope(
    unsigned short* __restrict__ Qbb, unsigned short* __restrict__ Kbb,
    const float* __restrict__ nq_w, const float* __restrict__ nq_b,
    const float* __restrict__ nk_w, const float* __restrict__ nk_b,
    const float* __restrict__ cosT, const float* __restrict__ sinT)
{
  const int w = threadIdx.x >> 6, lane = threadIdx.x & 63;
  const int idx = blockIdx.x * 4 + w;
  if (idx >= S_ * HEADS_) return;
  const int s = idx / HEADS_, h = idx % HEADS_;
  unsigned short* X = blockIdx.y ? Kbb : Qbb;
  const float* wt = blockIdx.y ? nk_w : nq_w;
  const float* bt = blockIdx.y ? nk_b : nq_b;
  const size_t off = (size_t)s * DIM_ + h * HD_ + lane;
  float x = b2f(X[off]);
  float m = x;
#pragma unroll
  for (int o = 32; o; o >>= 1) m += __shfl_xor(m, o);
  m *= (1.f / 64.f);
  float d = x - m;
  float v = d * d;
#pragma unroll
  for (int o = 32; o; o >>= 1) v += __shfl_xor(v, o);
  v *= (1.f / 64.f);
  float y = d * rsqrtf(v + 1e-6f) * wt[lane] + bt[lane];
  if (s >= T_) {
    float p = __shfl_xor(y, 1);
    float rot = (lane & 1) ? p : -p;
    int sv = s - T_;
    y = y * cosT[(size_t)sv * HD_ + lane] + rot * sinT[(size_t)sv * HD_ + lane];
  }
  if (!blockIdx.y) y *= 0.18033688011112042f;   // (1/8) * log2(e)
  X[off] = f2b(y);
}

// ============================================================================
extern "C" void kernel_launch(void* const* d_in, const int* in_sizes, int n_in,
                              void* d_out, int out_size, void* d_ws, size_t ws_size,
                              hipStream_t stream)
{
  const float* hidden  = (const float*)d_in[0];
  const float* encoder = (const float*)d_in[1];
  const float* cosT    = (const float*)d_in[2];
  const float* sinT    = (const float*)d_in[3];
  const float* to_q_w  = (const float*)d_in[4];
  const float* to_q_b  = (const float*)d_in[5];
  const float* to_k_w  = (const float*)d_in[6];
  const float* to_k_b  = (const float*)d_in[7];
  const float* to_v_w  = (const float*)d_in[8];
  const float* to_v_b  = (const float*)d_in[9];
  const float* nq_w    = (const float*)d_in[10];
  const float* nq_b    = (const float*)d_in[11];
  const float* nk_w    = (const float*)d_in[12];
  const float* nk_b    = (const float*)d_in[13];
  const float* conv1_w = (const float*)d_in[14];
  const float* conv2_w = (const float*)d_in[15];
  const float* to_out_w = (const float*)d_in[16];
  const float* to_out_b = (const float*)d_in[17];
  float* out = (float*)d_out;

  // ---- workspace layout: ~83.2 MB total (>=85.58 MB proven available) ----
  char* p = (char*)d_ws;
  unsigned short* hidpad = (unsigned short*)p;  p += (size_t)2560 * DIM_ * 2;        // 9.83 MB (later Opart0)
  unsigned short* y2b    = (unsigned short*)p;  p += (size_t)SV_ * DIM_ * 2;         // 7.86 MB
  unsigned short* wqkv   = (unsigned short*)p;  p += (size_t)3 * DIM_ * DIM_ * 2;    // 22.12 MB (later out_w bf16)
  unsigned short* w1p    = (unsigned short*)p;  p += (size_t)RANK_ * DIM_ * 3 * 2;   // 1.47 MB
  unsigned short* w2p    = (unsigned short*)p;  p += (size_t)DIM_ * RANK_ * 3 * 2;   // 1.47 MB
  unsigned short* QKbb   = (unsigned short*)p;  p += (size_t)2 * S_ * DIM_ * 2;      // 17.46 MB
  unsigned short* VbbT   = (unsigned short*)p;  p += (size_t)DIM_ * SP_ * 2;         // 8.85 MB
  unsigned short* encb   = (unsigned short*)p;  p += (size_t)T_ * DIM_ * 2;          // 0.87 MB
  float*          y1T    = (float*)p;           p += (size_t)12 * RANK_ * SV_ * 4;   // 12.58 MB (later Opart1+ml)
  unsigned short* gelup  = (unsigned short*)p;  p += (size_t)2560 * RANK_ * 2;       // 0.66 MB
  float*          bqkv   = (float*)p;           p += (size_t)3 * DIM_ * 4;           // 23 KB
  unsigned short* Qbb = QKbb;
  unsigned short* Kbb = QKbb + (size_t)S_ * DIM_;
  // split-S partial buffers overlay dead regions (hidpad, y1T)
  unsigned short* Op0 = hidpad;                          // 8.73 MB <= 9.83
  unsigned short* Op1 = (unsigned short*)y1T;            // 8.73 MB
  float*          ml  = (float*)((char*)y1T + (size_t)S_ * DIM_ * 2);  // 1.09 MB (fits)

  // ---- fused input conversions ----
  prep_all<<<(U5_ + 255) / 256, 256, 0, stream>>>(
      hidden, encoder, conv1_w, conv2_w, to_q_w, to_k_w, to_v_w,
      to_q_b, to_k_b, to_v_b, hidpad, encb, w1p, w2p, wqkv, bqkv);

  // ---- conv branch ----
  gemm_mfma<3, 0><<<dim3(SV_ / BN, 1, 12), 256, 0, stream>>>(
      w1p, nullptr, hidpad, nullptr, y1T, nullptr, RANK_, SV_, 480, DIM_ * 3, DIM_, 1);
  gelupad_k<<<(2560 * RANK_ + 255) / 256, 256, 0, stream>>>(y1T, gelup);
  gemm_mfma<1, 1><<<dim3(DIM_ / BN, SV_ / BM), 256, 0, stream>>>(
      gelup, nullptr, w2p, nullptr, y2b, nullptr, SV_, DIM_, RANK_ * 3, RANK_ * 3, RANK_ * 3, RANK_);

  // ---- fused QKV projection (bf16 out; V written transposed) ----
  const unsigned short* hid0 = hidpad + (size_t)256 * DIM_;
  gemm_mfma<2, 3><<<dim3(3 * DIM_ / BN, (S_ + BM - 1) / BM), 256, 0, stream>>>(
      encb, hid0, wqkv, bqkv, QKbb, VbbT, S_, 3 * DIM_, DIM_, DIM_, DIM_, 1);

  // ---- LN + RoPE (bf16 in place on Q,K; Q scaled log2e/8) ----
  qknorm_rope<<<dim3((S_ * HEADS_ + 3) / 4, 2), 256, 0, stream>>>(
      Qbb, Kbb, nq_w, nq_b, nk_w, nk_b, cosT, sinT);

  // ---- MFMA flash attention, split-S x2 (partials + ml) ----
  attn_mfma<<<dim3((S_ + 63) / 64, HEADS_, 2), 256, 0, stream>>>(
      Qbb, Kbb, VbbT, Op0, Op1, ml);

  // ---- LSE merge + conv-add -> Qbb; fused out-proj weight cvt -> wqkv ----
  merge_k<<<(MERGE_N_ + CVT_N_ + 255) / 256, 256, 0, stream>>>(
      Op0, Op1, ml, y2b, Qbb, to_out_w, wqkv);

  // ---- output projection -> d_out (fp32, tuple remap) ----
  gemm_mfma<0, 2><<<dim3(DIM_ / BN, (S_ + BM - 1) / BM), 256, 0, stream>>>(
      Qbb, nullptr, wqkv, to_out_b, out, nullptr, S_, DIM_, DIM_, DIM_, DIM_, 1);
}

// Round 13
// 381.784 us; speedup vs baseline: 1.0011x; 1.0011x over previous
//
#include <hip/hip_runtime.h>
#include <hip/hip_bf16.h>
#include <math.h>

#define F_     8
#define DIM_   1920
#define HEADS_ 30
#define HD_    64
#define RANK_  128
#define T_     226
#define SV_    2048
#define S_     2274
#define SP_    2304   // S_ padded to 64-key tiles (V^T leading-dim)

#define BM 128
#define BN 128
#define BK 32

using short8  = __attribute__((ext_vector_type(8))) short;
using f32x4   = __attribute__((ext_vector_type(4))) float;
using i32x4v  = __attribute__((ext_vector_type(4))) int;
using ushort4v= __attribute__((ext_vector_type(4))) unsigned short;

__device__ __forceinline__ unsigned short f2b(float f) {
  unsigned int u = __float_as_uint(f);
  u = (u + 0x7FFFu + ((u >> 16) & 1u)) >> 16;
  return (unsigned short)u;
}
__device__ __forceinline__ float b2f(unsigned short s) {
  return __uint_as_float(((unsigned int)s) << 16);
}
__device__ __forceinline__ void gload_lds16(const void* g, void* l) {
  __builtin_amdgcn_global_load_lds(
      (const __attribute__((address_space(1))) unsigned int*)g,
      (__attribute__((address_space(3))) unsigned int*)l, 16, 0, 0);
}
// bijective XCD-aware swizzle (m204)
__device__ __forceinline__ void xcd_swz(int& bx, int& by) {
  const int nx = gridDim.x;
  const int nwg = nx * gridDim.y;
  const int lid = by * nx + bx;
  const int q = nwg >> 3, r = nwg & 7;
  const int xcd = lid & 7, pos = lid >> 3;
  const int wg = (xcd < r ? xcd * (q + 1) : r * (q + 1) + (xcd - r) * q) + pos;
  bx = wg % nx; by = wg / nx;
}

// ============================================================================
// MFMA bf16 GEMM:  C(MxN) = A(MxK) @ B(NxK)^T [+ bias]
// AMODE 0: plain A; 1: conv shifts; 2: concat rows; 3: conv1 split-K x12
// OUTMODE 0: f32  1: bf16  2: f32 tuple-remap
//         3: bf16 QKV col-split; V (cols >= 2*DIM_) written TRANSPOSED to VT
// ============================================================================
template<int AMODE, int OUTMODE>
__global__ __launch_bounds__(256) void gemm_mfma(
    const unsigned short* __restrict__ A,
    const unsigned short* __restrict__ A2,
    const unsigned short* __restrict__ B,
    const float* __restrict__ bias,
    void* __restrict__ Cout,
    unsigned short* __restrict__ VT,
    int M, int N, int K, int lda, int ldb, int kinner)
{
  __shared__ __align__(16) unsigned short As[BM * BK];
  __shared__ __align__(16) unsigned short Bs[BN * BK];
  if constexpr (AMODE == 3) {
    const int z = blockIdx.z;
    A += (size_t)z * 480;
    B += (size_t)(z >> 2) * 256 * DIM_ + (z & 3) * 480;
    Cout = (void*)((float*)Cout + (size_t)z * M * N);
  }
  int bx = blockIdx.x, by = blockIdx.y;
  xcd_swz(bx, by);
  const int t   = threadIdx.x;
  const int w   = t >> 6, l = t & 63;
  const int wr  = w >> 1, wc = w & 1;
  const int row0 = by * BM, col0 = bx * BN;
  const int lr  = l & 15;
  const int lcg = l >> 4;
  const int sel = (lr >> 1) & 3;
  const int sr  = t >> 2;
  const int sc  = t & 3;

  f32x4 acc[4][4];
#pragma unroll
  for (int i = 0; i < 4; ++i)
#pragma unroll
    for (int j = 0; j < 4; ++j) acc[i][j] = (f32x4){0.f, 0.f, 0.f, 0.f};

  for (int k0 = 0; k0 < K; k0 += BK) {
    int kseg = 0, kcol = k0;
    if constexpr (AMODE == 1) { kseg = k0 / kinner; kcol = k0 - kseg * kinner; }
#pragma unroll
    for (int it = 0; it < 2; ++it) {
      const int r    = it * 64 + sr;
      const int csrc = sc ^ ((r >> 1) & 3);
      int ar = row0 + r; if (ar > M - 1) ar = M - 1;
      const unsigned short* asrc;
      if constexpr (AMODE == 1) {
        asrc = A + (size_t)(ar + kseg * 256) * kinner + kcol + csrc * 8;
      } else if constexpr (AMODE == 2) {
        asrc = (ar < T_) ? (A  + (size_t)ar        * DIM_ + k0 + csrc * 8)
                         : (A2 + (size_t)(ar - T_) * DIM_ + k0 + csrc * 8);
      } else {
        asrc = A + (size_t)ar * lda + k0 + csrc * 8;
      }
      gload_lds16(asrc, (char*)As + it * 4096 + t * 16);
      const unsigned short* bsrc = B + (size_t)(col0 + r) * ldb + k0 + csrc * 8;
      gload_lds16(bsrc, (char*)Bs + it * 4096 + t * 16);
    }
    __syncthreads();

    short8 af[4], bfv[4];
#pragma unroll
    for (int m = 0; m < 4; ++m) {
      int r = wr * 64 + m * 16 + lr;
      af[m] = *(const short8*)((const char*)As + r * 64 + ((lcg ^ sel) << 4));
    }
#pragma unroll
    for (int n = 0; n < 4; ++n) {
      int r = wc * 64 + n * 16 + lr;
      bfv[n] = *(const short8*)((const char*)Bs + r * 64 + ((lcg ^ sel) << 4));
    }
    __builtin_amdgcn_s_setprio(1);
#pragma unroll
    for (int m = 0; m < 4; ++m)
#pragma unroll
      for (int n = 0; n < 4; ++n)
        acc[m][n] = __builtin_amdgcn_mfma_f32_16x16x32_bf16(af[m], bfv[n], acc[m][n], 0, 0, 0);
    __builtin_amdgcn_s_setprio(0);
    __syncthreads();
  }

#pragma unroll
  for (int m = 0; m < 4; ++m) {
    const int rbase = row0 + wr * 64 + m * 16 + lcg * 4;
#pragma unroll
    for (int n = 0; n < 4; ++n) {
      const int c = col0 + wc * 64 + n * 16 + lr;
      const float bi = bias ? bias[c] : 0.f;
      if constexpr (OUTMODE == 3) {
        const int buf = c / DIM_, cc = c - buf * DIM_;
        if (buf == 2) {
          // V^T: [d=cc][key=r], 4 consecutive keys -> one 8B store
          unsigned short* vt = VT + (size_t)cc * SP_ + rbase;
          if (rbase + 4 <= M) {
            ushort4v o = {f2b(acc[m][n][0] + bi), f2b(acc[m][n][1] + bi),
                          f2b(acc[m][n][2] + bi), f2b(acc[m][n][3] + bi)};
            *(ushort4v*)vt = o;
          } else {
#pragma unroll
            for (int reg = 0; reg < 4; ++reg)
              if (rbase + reg < M) vt[reg] = f2b(acc[m][n][reg] + bi);
          }
        } else {
#pragma unroll
          for (int reg = 0; reg < 4; ++reg) {
            const int r = rbase + reg;
            if (r < M)
              ((unsigned short*)Cout)[(size_t)buf * S_ * DIM_ + (size_t)r * DIM_ + cc]
                  = f2b(acc[m][n][reg] + bi);
          }
        }
      } else {
#pragma unroll
        for (int reg = 0; reg < 4; ++reg) {
          const int r = rbase + reg;
          if (r >= M) continue;
          const float v = acc[m][n][reg] + bi;
          if constexpr (OUTMODE == 0) {
            ((float*)Cout)[(size_t)r * N + c] = v;
          } else if constexpr (OUTMODE == 1) {
            ((unsigned short*)Cout)[(size_t)r * N + c] = f2b(v);
          } else {
            const size_t orow = (r >= T_) ? (size_t)(r - T_) : (size_t)(SV_ + r);
            ((float*)Cout)[orow * N + c] = v;
          }
        }
      }
    }
  }
}

// P-fragment exchange: 8 bpermutes -> one A-frag (verified mapping)
__device__ __forceinline__ short8 build_pa(int c0lo, int c0hi, int c1lo, int c1hi,
                                           int addrA, bool hi_m) {
  const int a0 = __builtin_amdgcn_ds_bpermute(addrA,      c0lo);
  const int b0 = __builtin_amdgcn_ds_bpermute(addrA,      c1lo);
  const int a1 = __builtin_amdgcn_ds_bpermute(addrA,      c0hi);
  const int b1 = __builtin_amdgcn_ds_bpermute(addrA,      c1hi);
  const int a2 = __builtin_amdgcn_ds_bpermute(addrA + 64, c0lo);
  const int b2 = __builtin_amdgcn_ds_bpermute(addrA + 64, c1lo);
  const int a3 = __builtin_amdgcn_ds_bpermute(addrA + 64, c0hi);
  const int b3 = __builtin_amdgcn_ds_bpermute(addrA + 64, c1hi);
  i32x4v pw;
  pw[0] = hi_m ? b0 : a0;
  pw[1] = hi_m ? b1 : a1;
  pw[2] = hi_m ? b2 : a2;
  pw[3] = hi_m ? b3 : a3;
  return __builtin_bit_cast(short8, pw);
}

// ============================================================================
// MFMA flash attention, split-S x2, QBLK=64.
// BOTH K and V^T staged in LDS via global_load_lds (dbuf, pre-swizzled src) —
// single vmcnt/DMA queue, drained once per tile at the barrier.
// No ds_write, no reg round-trip. LDS = 32 KB.
// Writes UNNORMALIZED O-partial (bf16) + per-(q,h) {m,l} (f32) for LSE merge.
// ============================================================================
__global__ __launch_bounds__(256) void attn_mfma(
    const unsigned short* __restrict__ Qbb,
    const unsigned short* __restrict__ Kbb,
    const unsigned short* __restrict__ VT,
    unsigned short* __restrict__ Op0,
    unsigned short* __restrict__ Op1,
    float* __restrict__ ml)
{
  __shared__ __align__(16) unsigned short Kl[2][64 * 64];   // [key][d], swz 16B
  __shared__ __align__(16) unsigned short Vl[2][64 * 64];   // [d][key], swz 16B

  const int sv = blockIdx.z;
  int bx = blockIdx.x, by = blockIdx.y;
  xcd_swz(bx, by);
  const int qb = bx, h = by;
  const int t = threadIdx.x, w = t >> 6, l = t & 63;
  const int lr = l & 15, lg = l >> 4;
  const int q0 = qb * 64;
  const int j0base = sv * 1152;
  const int NT = 18;
  unsigned short* Opart = sv ? Op1 : Op0;

  short8 qa[2];
  {
    int qrow = q0 + w * 16 + lr; if (qrow >= S_) qrow = S_ - 1;
    const unsigned short* qp = Qbb + (size_t)qrow * DIM_ + h * 64 + lg * 8;
    qa[0] = *(const short8*)qp;
    qa[1] = *(const short8*)(qp + 32);
  }

  // staging constants: row within 64-row tile, pre-swizzled col (involution)
  const int srow = t >> 3;                 // +32 for second half
  const int sc0 = ((((t & 7) * 16) ^ ((srow        & 7) << 4)) >> 1);  // ushorts
  const int sc1 = ((((t & 7) * 16) ^ (((srow + 32) & 7) << 4)) >> 1);
  // V^T source rows for this thread (d rows are always valid)
  const unsigned short* vsrc0 = VT + (size_t)(h * 64 + srow)      * SP_ + sc0;
  const unsigned short* vsrc1 = VT + (size_t)(h * 64 + srow + 32) * SP_ + sc1;

  f32x4 oacc[4];
#pragma unroll
  for (int n = 0; n < 4; ++n) oacc[n] = (f32x4){0.f, 0.f, 0.f, 0.f};
  float m_run = -1e30f, l_run = 0.f;

  const int addrA = (lr + ((lg & 1) << 5)) << 2;
  const bool hi_m = (lg & 2) != 0;

  // ---- prologue: stage K+V tile 0 of this half ----
  {
    int k0 = j0base + srow;      if (k0 >= S_) k0 = S_ - 1;
    int k1 = j0base + srow + 32; if (k1 >= S_) k1 = S_ - 1;
    gload_lds16(Kbb + (size_t)k0 * DIM_ + h * 64 + sc0, (char*)Kl[0] + t * 16);
    gload_lds16(Kbb + (size_t)k1 * DIM_ + h * 64 + sc1, (char*)Kl[0] + 4096 + t * 16);
    gload_lds16(vsrc0 + j0base, (char*)Vl[0] + t * 16);
    gload_lds16(vsrc1 + j0base, (char*)Vl[0] + 4096 + t * 16);
  }
  __syncthreads();

  for (int jt = 0; jt < NT; ++jt) {
    const int j0 = j0base + jt * 64;
    const int cur = jt & 1;

    // ---- issue K+V prefetch for next tile (clamped re-read on last iter) --
    const int jn0 = (jt + 1 < NT) ? j0 + 64 : j0;
    {
      int k0 = jn0 + srow;      if (k0 >= S_) k0 = S_ - 1;
      int k1 = jn0 + srow + 32; if (k1 >= S_) k1 = S_ - 1;
      gload_lds16(Kbb + (size_t)k0 * DIM_ + h * 64 + sc0,
                  (char*)Kl[cur ^ 1] + t * 16);
      gload_lds16(Kbb + (size_t)k1 * DIM_ + h * 64 + sc1,
                  (char*)Kl[cur ^ 1] + 4096 + t * 16);
      gload_lds16(vsrc0 + jn0, (char*)Vl[cur ^ 1] + t * 16);
      gload_lds16(vsrc1 + jn0, (char*)Vl[cur ^ 1] + 4096 + t * 16);
    }

    // ---- S^T = K @ Q^T : lane holds S[key = m*16+lg*4+r][q = lr] ----
    f32x4 sacc[4];
#pragma unroll
    for (int m = 0; m < 4; ++m) sacc[m] = (f32x4){0.f, 0.f, 0.f, 0.f};
    __builtin_amdgcn_s_setprio(1);
#pragma unroll
    for (int m = 0; m < 4; ++m) {
#pragma unroll
      for (int ks = 0; ks < 2; ++ks) {
        const short8 kb = *(const short8*)((const char*)Kl[cur] + (m * 16 + lr) * 128 +
                              ((ks * 64 + lg * 16) ^ ((lr & 7) << 4)));
        sacc[m] = __builtin_amdgcn_mfma_f32_16x16x32_bf16(kb, qa[ks], sacc[m], 0, 0, 0);
      }
    }
    __builtin_amdgcn_s_setprio(0);

    if (j0 + 64 > S_) {
#pragma unroll
      for (int m = 0; m < 4; ++m)
#pragma unroll
        for (int r = 0; r < 4; ++r)
          if (j0 + m * 16 + lg * 4 + r >= S_) sacc[m][r] = -1e30f;
    }

    // ---- row max ----
    float mx = sacc[0][0];
#pragma unroll
    for (int m = 0; m < 4; ++m)
#pragma unroll
      for (int r = 0; r < 4; ++r) mx = fmaxf(mx, sacc[m][r]);
    mx = fmaxf(mx, __shfl_xor(mx, 16));
    mx = fmaxf(mx, __shfl_xor(mx, 32));

    // ---- defer-max rescale (exp2 domain, THR=8) ----
    if (!__all(mx <= m_run + 8.0f)) {
      const float mnew = fmaxf(m_run, mx);
      const float sc = exp2f(m_run - mnew);
      l_run *= sc;
      float scr[4];
#pragma unroll
      for (int r = 0; r < 4; ++r) scr[r] = __shfl(sc, (l & 48) | (lg * 4 + r));
#pragma unroll
      for (int n = 0; n < 4; ++n)
#pragma unroll
        for (int r = 0; r < 4; ++r) oacc[n][r] *= scr[r];
      m_run = mnew;
    }

    // ---- P = exp2(S - m), packed to bf16 pairs in-register ----
    float rs = 0.f;
    int c[4][2];
#pragma unroll
    for (int m = 0; m < 4; ++m) {
      const float p0 = exp2f(sacc[m][0] - m_run);
      const float p1 = exp2f(sacc[m][1] - m_run);
      const float p2 = exp2f(sacc[m][2] - m_run);
      const float p3 = exp2f(sacc[m][3] - m_run);
      rs += (p0 + p1) + (p2 + p3);
      asm("v_cvt_pk_bf16_f32 %0, %1, %2" : "=v"(c[m][0]) : "v"(p0), "v"(p1));
      asm("v_cvt_pk_bf16_f32 %0, %1, %2" : "=v"(c[m][1]) : "v"(p2), "v"(p3));
    }
    rs += __shfl_xor(rs, 16);
    rs += __shfl_xor(rs, 32);
    l_run += rs;

    // ---- P A-frags via bpermute, then O += P @ V (V^T from LDS) ----
    __builtin_amdgcn_s_setprio(1);
    {
      const short8 pa0 = build_pa(c[0][0], c[0][1], c[1][0], c[1][1], addrA, hi_m);
#pragma unroll
      for (int n = 0; n < 4; ++n) {
        const short8 vb = *(const short8*)((const char*)Vl[cur] + (n * 16 + lr) * 128 +
                              ((0 * 64 + lg * 16) ^ ((lr & 7) << 4)));
        oacc[n] = __builtin_amdgcn_mfma_f32_16x16x32_bf16(pa0, vb, oacc[n], 0, 0, 0);
      }
      const short8 pa1 = build_pa(c[2][0], c[2][1], c[3][0], c[3][1], addrA, hi_m);
#pragma unroll
      for (int n = 0; n < 4; ++n) {
        const short8 vb = *(const short8*)((const char*)Vl[cur] + (n * 16 + lr) * 128 +
                              ((1 * 64 + lg * 16) ^ ((lr & 7) << 4)));
        oacc[n] = __builtin_amdgcn_mfma_f32_16x16x32_bf16(pa1, vb, oacc[n], 0, 0, 0);
      }
    }
    __builtin_amdgcn_s_setprio(0);

    __syncthreads();     // drains K+V DMA; Kl/Vl[cur^1] ready for next iter
  }

  // ---- epilogue: store UNNORMALIZED partial + {m,l} ----
#pragma unroll
  for (int r = 0; r < 4; ++r) {
    const int row = q0 + w * 16 + lg * 4 + r;
    if (row >= S_) continue;
#pragma unroll
    for (int n = 0; n < 4; ++n)
      Opart[(size_t)row * DIM_ + h * 64 + n * 16 + lr] = f2b(oacc[n][r]);
  }
  if (l < 16) {                       // lg==0 lane holds (m,l) for q = lr
    const int row = q0 + w * 16 + lr;
    if (row < S_) {
      float2 v; v.x = m_run; v.y = l_run;
      *(float2*)(ml + ((size_t)(sv * S_ + row) * HEADS_ + h) * 2) = v;
    }
  }
}

// ============================================================================
// merge split-S partials (LSE combine) + conv-branch add -> bf16
// fused tail range: out-proj weight f32 -> bf16 (x8 vectorized)
// ============================================================================
#define MERGE_N_ (S_ * DIM_ / 8)
#define CVT_N_   (DIM_ * DIM_ / 8)
__global__ void merge_k(const unsigned short* __restrict__ Op0,
                        const unsigned short* __restrict__ Op1,
                        const float* __restrict__ ml,
                        const unsigned short* __restrict__ y2b,
                        unsigned short* __restrict__ dst,
                        const float* __restrict__ ow,
                        unsigned short* __restrict__ owb)
{
  const int i = blockIdx.x * 256 + threadIdx.x;
  if (i < MERGE_N_) {
    const int e = i * 8;
    const int row = e / DIM_, col = e % DIM_;
    const int h = col >> 6;
    const float* p0 = ml + ((size_t)row * HEADS_ + h) * 2;
    const float* p1 = ml + ((size_t)(S_ + row) * HEADS_ + h) * 2;
    const float m0 = p0[0], l0 = p0[1], m1 = p1[0], l1 = p1[1];
    const float M = fmaxf(m0, m1);
    const float w0 = exp2f(m0 - M), w1 = exp2f(m1 - M);
    const float inv = 1.f / (w0 * l0 + w1 * l1);
    const short8 a = *(const short8*)(Op0 + e);
    const short8 b = *(const short8*)(Op1 + e);
    const bool cadd = row >= T_;
    const unsigned short* yp = y2b + (size_t)(row - T_) * DIM_ + col;
    short8 o;
#pragma unroll
    for (int j = 0; j < 8; ++j) {
      float v = (w0 * b2f((unsigned short)a[j]) + w1 * b2f((unsigned short)b[j])) * inv;
      if (cadd) v += b2f(yp[j]);
      o[j] = (short)f2b(v);
    }
    *(short8*)(dst + e) = o;
  } else if (i < MERGE_N_ + CVT_N_) {
    const int e = (i - MERGE_N_) * 8;
    const float4 v0 = *(const float4*)(ow + e);
    const float4 v1 = *(const float4*)(ow + e + 4);
    short8 o;
    o[0]=(short)f2b(v0.x); o[1]=(short)f2b(v0.y); o[2]=(short)f2b(v0.z); o[3]=(short)f2b(v0.w);
    o[4]=(short)f2b(v1.x); o[5]=(short)f2b(v1.y); o[6]=(short)f2b(v1.z); o[7]=(short)f2b(v1.w);
    *(short8*)(owb + e) = o;
  }
}

// ============================================================================
// fused input conversions (one launch)
// ============================================================================
#define U0_ 1228800
#define U1_ 3993600
#define U2_ 4427520
#define U3_ 5164800
#define U4_ 5902080
#define U5_ 5907840
__global__ void prep_all(const float* __restrict__ hid, const float* __restrict__ enc,
                         const float* __restrict__ w1, const float* __restrict__ w2,
                         const float* __restrict__ qw, const float* __restrict__ kw,
                         const float* __restrict__ vw, const float* __restrict__ qb2,
                         const float* __restrict__ kb2, const float* __restrict__ vb2,
                         unsigned short* __restrict__ hidpad, unsigned short* __restrict__ encb,
                         unsigned short* __restrict__ w1p, unsigned short* __restrict__ w2p,
                         unsigned short* __restrict__ wqkv, float* __restrict__ bqkv)
{
  const int i = blockIdx.x * 256 + threadIdx.x;
  if (i < U0_) {                                   // hidpad (zero-padded), x4
    const int e = i * 4;
    const int r = e / DIM_;
    ushort4v o = (ushort4v){0, 0, 0, 0};
    if (r >= 256 && r < 256 + SV_) {
      const float4 v = *(const float4*)(hid + e - 256 * DIM_);
      o[0] = f2b(v.x); o[1] = f2b(v.y); o[2] = f2b(v.z); o[3] = f2b(v.w);
    }
    *(ushort4v*)(hidpad + e) = o;
  } else if (i < U1_) {                            // fused QKV weights, x4
    const int e = (i - U0_) * 4;
    const int which = e / (DIM_ * DIM_);
    const int j = e - which * DIM_ * DIM_;
    const float* s = which == 0 ? qw : which == 1 ? kw : vw;
    const float4 v = *(const float4*)(s + j);
    ushort4v o = {f2b(v.x), f2b(v.y), f2b(v.z), f2b(v.w)};
    *(ushort4v*)(wqkv + e) = o;
  } else if (i < U2_) {                            // encoder bf16
    const int e = i - U1_;
    encb[e] = f2b(enc[e]);
  } else if (i < U3_) {                            // conv1 w permute
    const int e = i - U2_;
    const int oc = e / (DIM_ * 3), rem = e % (DIM_ * 3);
    const int ks = rem / DIM_, ic = rem % DIM_;
    w1p[e] = f2b(w1[(size_t)oc * DIM_ * 3 + ic * 3 + ks]);
  } else if (i < U4_) {                            // conv2 w permute
    const int e = i - U3_;
    const int oc = e / (RANK_ * 3), rem = e % (RANK_ * 3);
    const int ks = rem / RANK_, rc = rem % RANK_;
    w2p[e] = f2b(w2[(size_t)oc * RANK_ * 3 + rc * 3 + ks]);
  } else if (i < U5_) {                            // fused QKV bias (f32)
    const int e = i - U4_;
    const int which = e / DIM_, j = e % DIM_;
    bqkv[e] = which == 0 ? qb2[j] : which == 1 ? kb2[j] : vb2[j];
  }
}

// sum 12 split-K partials of y1^T [128][2048], GELU, write padded [2560][128]
__global__ void gelupad_k(const float* __restrict__ y1T, unsigned short* __restrict__ dst)
{
  int i = blockIdx.x * 256 + threadIdx.x;
  if (i >= 2560 * RANK_) return;
  int r = i / RANK_, rc = i % RANK_;
  unsigned short o = 0;
  if (r >= 256 && r < 256 + SV_) {
    int s = r - 256;
    float x = 0.f;
#pragma unroll
    for (int z = 0; z < 12; ++z)
      x += y1T[(size_t)z * RANK_ * SV_ + (size_t)rc * SV_ + s];
    o = f2b(0.5f * x * (1.f + erff(x * 0.70710678118654752f)));
  }
  dst[i] = o;
}

// LN over HD=64 + RoPE, bf16 in place; Q branch scaled by log2(e)/8
__global__ __launch_bounds__(256) void qknorm_rope(
    unsigned short* __restrict__ Qbb, unsigned short* __restrict__ Kbb,
    const float* __restrict__ nq_w, const float* __restrict__ nq_b,
    const float* __restrict__ nk_w, const float* __restrict__ nk_b,
    const float* __restrict__ cosT, const float* __restrict__ sinT)
{
  const int w = threadIdx.x >> 6, lane = threadIdx.x & 63;
  const int idx = blockIdx.x * 4 + w;
  if (idx >= S_ * HEADS_) return;
  const int s = idx / HEADS_, h = idx % HEADS_;
  unsigned short* X = blockIdx.y ? Kbb : Qbb;
  const float* wt = blockIdx.y ? nk_w : nq_w;
  const float* bt = blockIdx.y ? nk_b : nq_b;
  const size_t off = (size_t)s * DIM_ + h * HD_ + lane;
  float x = b2f(X[off]);
  float m = x;
#pragma unroll
  for (int o = 32; o; o >>= 1) m += __shfl_xor(m, o);
  m *= (1.f / 64.f);
  float d = x - m;
  float v = d * d;
#pragma unroll
  for (int o = 32; o; o >>= 1) v += __shfl_xor(v, o);
  v *= (1.f / 64.f);
  float y = d * rsqrtf(v + 1e-6f) * wt[lane] + bt[lane];
  if (s >= T_) {
    float p = __shfl_xor(y, 1);
    float rot = (lane & 1) ? p : -p;
    int sv = s - T_;
    y = y * cosT[(size_t)sv * HD_ + lane] + rot * sinT[(size_t)sv * HD_ + lane];
  }
  if (!blockIdx.y) y *= 0.18033688011112042f;   // (1/8) * log2(e)
  X[off] = f2b(y);
}

// ============================================================================
extern "C" void kernel_launch(void* const* d_in, const int* in_sizes, int n_in,
                              void* d_out, int out_size, void* d_ws, size_t ws_size,
                              hipStream_t stream)
{
  const float* hidden  = (const float*)d_in[0];
  const float* encoder = (const float*)d_in[1];
  const float* cosT    = (const float*)d_in[2];
  const float* sinT    = (const float*)d_in[3];
  const float* to_q_w  = (const float*)d_in[4];
  const float* to_q_b  = (const float*)d_in[5];
  const float* to_k_w  = (const float*)d_in[6];
  const float* to_k_b  = (const float*)d_in[7];
  const float* to_v_w  = (const float*)d_in[8];
  const float* to_v_b  = (const float*)d_in[9];
  const float* nq_w    = (const float*)d_in[10];
  const float* nq_b    = (const float*)d_in[11];
  const float* nk_w    = (const float*)d_in[12];
  const float* nk_b    = (const float*)d_in[13];
  const float* conv1_w = (const float*)d_in[14];
  const float* conv2_w = (const float*)d_in[15];
  const float* to_out_w = (const float*)d_in[16];
  const float* to_out_b = (const float*)d_in[17];
  float* out = (float*)d_out;

  // ---- workspace layout: ~83.2 MB total (>=85.58 MB proven available) ----
  char* p = (char*)d_ws;
  unsigned short* hidpad = (unsigned short*)p;  p += (size_t)2560 * DIM_ * 2;        // 9.83 MB (later Opart0)
  unsigned short* y2b    = (unsigned short*)p;  p += (size_t)SV_ * DIM_ * 2;         // 7.86 MB
  unsigned short* wqkv   = (unsigned short*)p;  p += (size_t)3 * DIM_ * DIM_ * 2;    // 22.12 MB (later out_w bf16)
  unsigned short* w1p    = (unsigned short*)p;  p += (size_t)RANK_ * DIM_ * 3 * 2;   // 1.47 MB
  unsigned short* w2p    = (unsigned short*)p;  p += (size_t)DIM_ * RANK_ * 3 * 2;   // 1.47 MB
  unsigned short* QKbb   = (unsigned short*)p;  p += (size_t)2 * S_ * DIM_ * 2;      // 17.46 MB
  unsigned short* VbbT   = (unsigned short*)p;  p += (size_t)DIM_ * SP_ * 2;         // 8.85 MB
  unsigned short* encb   = (unsigned short*)p;  p += (size_t)T_ * DIM_ * 2;          // 0.87 MB
  float*          y1T    = (float*)p;           p += (size_t)12 * RANK_ * SV_ * 4;   // 12.58 MB (later Opart1+ml)
  unsigned short* gelup  = (unsigned short*)p;  p += (size_t)2560 * RANK_ * 2;       // 0.66 MB
  float*          bqkv   = (float*)p;           p += (size_t)3 * DIM_ * 4;           // 23 KB
  unsigned short* Qbb = QKbb;
  unsigned short* Kbb = QKbb + (size_t)S_ * DIM_;
  // split-S partial buffers overlay dead regions (hidpad, y1T)
  unsigned short* Op0 = hidpad;                          // 8.73 MB <= 9.83
  unsigned short* Op1 = (unsigned short*)y1T;            // 8.73 MB
  float*          ml  = (float*)((char*)y1T + (size_t)S_ * DIM_ * 2);  // 1.09 MB (fits)

  // ---- fused input conversions ----
  prep_all<<<(U5_ + 255) / 256, 256, 0, stream>>>(
      hidden, encoder, conv1_w, conv2_w, to_q_w, to_k_w, to_v_w,
      to_q_b, to_k_b, to_v_b, hidpad, encb, w1p, w2p, wqkv, bqkv);

  // ---- conv branch ----
  gemm_mfma<3, 0><<<dim3(SV_ / BN, 1, 12), 256, 0, stream>>>(
      w1p, nullptr, hidpad, nullptr, y1T, nullptr, RANK_, SV_, 480, DIM_ * 3, DIM_, 1);
  gelupad_k<<<(2560 * RANK_ + 255) / 256, 256, 0, stream>>>(y1T, gelup);
  gemm_mfma<1, 1><<<dim3(DIM_ / BN, SV_ / BM), 256, 0, stream>>>(
      gelup, nullptr, w2p, nullptr, y2b, nullptr, SV_, DIM_, RANK_ * 3, RANK_ * 3, RANK_ * 3, RANK_);

  // ---- fused QKV projection (bf16 out; V written transposed) ----
  const unsigned short* hid0 = hidpad + (size_t)256 * DIM_;
  gemm_mfma<2, 3><<<dim3(3 * DIM_ / BN, (S_ + BM - 1) / BM), 256, 0, stream>>>(
      encb, hid0, wqkv, bqkv, QKbb, VbbT, S_, 3 * DIM_, DIM_, DIM_, DIM_, 1);

  // ---- LN + RoPE (bf16 in place on Q,K; Q scaled log2e/8) ----
  qknorm_rope<<<dim3((S_ * HEADS_ + 3) / 4, 2), 256, 0, stream>>>(
      Qbb, Kbb, nq_w, nq_b, nk_w, nk_b, cosT, sinT);

  // ---- MFMA flash attention, split-S x2 (partials + ml) ----
  attn_mfma<<<dim3((S_ + 63) / 64, HEADS_, 2), 256, 0, stream>>>(
      Qbb, Kbb, VbbT, Op0, Op1, ml);

  // ---- LSE merge + conv-add -> Qbb; fused out-proj weight cvt -> wqkv ----
  merge_k<<<(MERGE_N_ + CVT_N_ + 255) / 256, 256, 0, stream>>>(
      Op0, Op1, ml, y2b, Qbb, to_out_w, wqkv);

  // ---- output projection -> d_out (fp32, tuple remap) ----
  gemm_mfma<0, 2><<<dim3(DIM_ / BN, (S_ + BM - 1) / BM), 256, 0, stream>>>(
      Qbb, nullptr, wqkv, to_out_b, out, nullptr, S_, DIM_, DIM_, DIM_, DIM_, 1);
}

// Round 14
// 343.244 us; speedup vs baseline: 1.1135x; 1.1123x over previous
//
#include <hip/hip_runtime.h>
#include <hip/hip_bf16.h>
#include <math.h>

#define F_     8
#define DIM_   1920
#define HEADS_ 30
#define HD_    64
#define RANK_  128
#define T_     226
#define SV_    2048
#define S_     2274
#define SP_    2304   // S_ padded to 64-key tiles (V^T leading-dim)
#define NS_    3      // split-S factor
#define NTS_   12     // key tiles per split (3*12*64 = 2304 >= S_)

#define BM 128
#define BN 128

using short8  = __attribute__((ext_vector_type(8))) short;
using f32x4   = __attribute__((ext_vector_type(4))) float;
using i32x4v  = __attribute__((ext_vector_type(4))) int;
using ushort4v= __attribute__((ext_vector_type(4))) unsigned short;

__device__ __forceinline__ unsigned short f2b(float f) {
  unsigned int u = __float_as_uint(f);
  u = (u + 0x7FFFu + ((u >> 16) & 1u)) >> 16;
  return (unsigned short)u;
}
__device__ __forceinline__ float b2f(unsigned short s) {
  return __uint_as_float(((unsigned int)s) << 16);
}
__device__ __forceinline__ void gload_lds16(const void* g, void* l) {
  __builtin_amdgcn_global_load_lds(
      (const __attribute__((address_space(1))) unsigned int*)g,
      (__attribute__((address_space(3))) unsigned int*)l, 16, 0, 0);
}
// bijective XCD-aware swizzle (m204)
__device__ __forceinline__ void xcd_swz(int& bx, int& by) {
  const int nx = gridDim.x;
  const int nwg = nx * gridDim.y;
  const int lid = by * nx + bx;
  const int q = nwg >> 3, r = nwg & 7;
  const int xcd = lid & 7, pos = lid >> 3;
  const int wg = (xcd < r ? xcd * (q + 1) : r * (q + 1) + (xcd - r) * q) + pos;
  bx = wg % nx; by = wg / nx;
}

// ============================================================================
// MFMA bf16 GEMM:  C(MxN) = A(MxK) @ B(NxK)^T [+ bias]
// AMODE 0: plain A; 1: conv shifts; 2: concat rows; 3: conv1 split-K x12
// OUTMODE 0: f32  1: bf16  2: f32 tuple-remap
//         3: bf16 QKV col-split; V (cols >= 2*DIM_) written TRANSPOSED to VT
// BKT: 32 (4-slot swizzle) or 64 (8-slot swizzle, halves barrier count).
// ============================================================================
template<int AMODE, int OUTMODE, int BKT>
__global__ __launch_bounds__(256) void gemm_mfma(
    const unsigned short* __restrict__ A,
    const unsigned short* __restrict__ A2,
    const unsigned short* __restrict__ B,
    const float* __restrict__ bias,
    void* __restrict__ Cout,
    unsigned short* __restrict__ VT,
    int M, int N, int K, int lda, int ldb, int kinner)
{
  __shared__ __align__(16) unsigned short As[BM * BKT];
  __shared__ __align__(16) unsigned short Bs[BN * BKT];
  if constexpr (AMODE == 3) {
    const int z = blockIdx.z;
    A += (size_t)z * 480;
    B += (size_t)(z >> 2) * 256 * DIM_ + (z & 3) * 480;
    Cout = (void*)((float*)Cout + (size_t)z * M * N);
  }
  int bx = blockIdx.x, by = blockIdx.y;
  xcd_swz(bx, by);
  const int t   = threadIdx.x;
  const int w   = t >> 6, l = t & 63;
  const int wr  = w >> 1, wc = w & 1;
  const int row0 = by * BM, col0 = bx * BN;
  const int lr  = l & 15;
  const int lcg = l >> 4;

  f32x4 acc[4][4];
#pragma unroll
  for (int i = 0; i < 4; ++i)
#pragma unroll
    for (int j = 0; j < 4; ++j) acc[i][j] = (f32x4){0.f, 0.f, 0.f, 0.f};

  for (int k0 = 0; k0 < K; k0 += BKT) {
    int kseg = 0, kcol = k0;
    if constexpr (AMODE == 1) { kseg = k0 / kinner; kcol = k0 - kseg * kinner; }

    if constexpr (BKT == 32) {
      const int sr = t >> 2, sc = t & 3;
#pragma unroll
      for (int it = 0; it < 2; ++it) {
        const int r    = it * 64 + sr;
        const int csrc = sc ^ ((r >> 1) & 3);
        int ar = row0 + r; if (ar > M - 1) ar = M - 1;
        const unsigned short* asrc;
        if constexpr (AMODE == 1) {
          asrc = A + (size_t)(ar + kseg * 256) * kinner + kcol + csrc * 8;
        } else if constexpr (AMODE == 2) {
          asrc = (ar < T_) ? (A  + (size_t)ar        * DIM_ + k0 + csrc * 8)
                           : (A2 + (size_t)(ar - T_) * DIM_ + k0 + csrc * 8);
        } else {
          asrc = A + (size_t)ar * lda + k0 + csrc * 8;
        }
        gload_lds16(asrc, (char*)As + it * 4096 + t * 16);
        const unsigned short* bsrc = B + (size_t)(col0 + it * 64 + sr) * ldb + k0 + csrc * 8;
        gload_lds16(bsrc, (char*)Bs + it * 4096 + t * 16);
      }
      __syncthreads();
      const int sel = (lr >> 1) & 3;
      short8 af[4], bfv[4];
#pragma unroll
      for (int m = 0; m < 4; ++m)
        af[m] = *(const short8*)((const char*)As + (wr * 64 + m * 16 + lr) * 64 + ((lcg ^ sel) << 4));
#pragma unroll
      for (int n = 0; n < 4; ++n)
        bfv[n] = *(const short8*)((const char*)Bs + (wc * 64 + n * 16 + lr) * 64 + ((lcg ^ sel) << 4));
      __builtin_amdgcn_s_setprio(1);
#pragma unroll
      for (int m = 0; m < 4; ++m)
#pragma unroll
        for (int n = 0; n < 4; ++n)
          acc[m][n] = __builtin_amdgcn_mfma_f32_16x16x32_bf16(af[m], bfv[n], acc[m][n], 0, 0, 0);
      __builtin_amdgcn_s_setprio(0);
      __syncthreads();
    } else {
      // BKT == 64: rows are 128B, 8 slots of 16B; involution slot^=(row&7)
      const int srow8 = (t >> 3) & 7;            // row&7, same for all 4 its
      const int csrc  = (t & 7) ^ srow8;         // pre-swizzled source slot
#pragma unroll
      for (int it = 0; it < 4; ++it) {
        const int r = it * 32 + (t >> 3);
        int ar = row0 + r; if (ar > M - 1) ar = M - 1;
        const unsigned short* asrc;
        if constexpr (AMODE == 1) {
          asrc = A + (size_t)(ar + kseg * 256) * kinner + kcol + csrc * 8;
        } else if constexpr (AMODE == 2) {
          asrc = (ar < T_) ? (A  + (size_t)ar        * DIM_ + k0 + csrc * 8)
                           : (A2 + (size_t)(ar - T_) * DIM_ + k0 + csrc * 8);
        } else {
          asrc = A + (size_t)ar * lda + k0 + csrc * 8;
        }
        gload_lds16(asrc, (char*)As + it * 4096 + t * 16);
        const unsigned short* bsrc = B + (size_t)(col0 + r) * ldb + k0 + csrc * 8;
        gload_lds16(bsrc, (char*)Bs + it * 4096 + t * 16);
      }
      __syncthreads();
#pragma unroll
      for (int kh = 0; kh < 2; ++kh) {
        const int sl = ((kh * 4 + lcg) ^ (lr & 7)) << 4;
        short8 af[4], bfv[4];
#pragma unroll
        for (int m = 0; m < 4; ++m)
          af[m] = *(const short8*)((const char*)As + (wr * 64 + m * 16 + lr) * 128 + sl);
#pragma unroll
        for (int n = 0; n < 4; ++n)
          bfv[n] = *(const short8*)((const char*)Bs + (wc * 64 + n * 16 + lr) * 128 + sl);
        __builtin_amdgcn_s_setprio(1);
#pragma unroll
        for (int m = 0; m < 4; ++m)
#pragma unroll
          for (int n = 0; n < 4; ++n)
            acc[m][n] = __builtin_amdgcn_mfma_f32_16x16x32_bf16(af[m], bfv[n], acc[m][n], 0, 0, 0);
        __builtin_amdgcn_s_setprio(0);
      }
      __syncthreads();
    }
  }

#pragma unroll
  for (int m = 0; m < 4; ++m) {
    const int rbase = row0 + wr * 64 + m * 16 + lcg * 4;
#pragma unroll
    for (int n = 0; n < 4; ++n) {
      const int c = col0 + wc * 64 + n * 16 + lr;
      const float bi = bias ? bias[c] : 0.f;
      if constexpr (OUTMODE == 3) {
        const int buf = c / DIM_, cc = c - buf * DIM_;
        if (buf == 2) {
          unsigned short* vt = VT + (size_t)cc * SP_ + rbase;
          if (rbase + 4 <= M) {
            ushort4v o = {f2b(acc[m][n][0] + bi), f2b(acc[m][n][1] + bi),
                          f2b(acc[m][n][2] + bi), f2b(acc[m][n][3] + bi)};
            *(ushort4v*)vt = o;
          } else {
#pragma unroll
            for (int reg = 0; reg < 4; ++reg)
              if (rbase + reg < M) vt[reg] = f2b(acc[m][n][reg] + bi);
          }
        } else {
#pragma unroll
          for (int reg = 0; reg < 4; ++reg) {
            const int r = rbase + reg;
            if (r < M)
              ((unsigned short*)Cout)[(size_t)buf * S_ * DIM_ + (size_t)r * DIM_ + cc]
                  = f2b(acc[m][n][reg] + bi);
          }
        }
      } else {
#pragma unroll
        for (int reg = 0; reg < 4; ++reg) {
          const int r = rbase + reg;
          if (r >= M) continue;
          const float v = acc[m][n][reg] + bi;
          if constexpr (OUTMODE == 0) {
            ((float*)Cout)[(size_t)r * N + c] = v;
          } else if constexpr (OUTMODE == 1) {
            ((unsigned short*)Cout)[(size_t)r * N + c] = f2b(v);
          } else {
            const size_t orow = (r >= T_) ? (size_t)(r - T_) : (size_t)(SV_ + r);
            ((float*)Cout)[orow * N + c] = v;
          }
        }
      }
    }
  }
}

// P-fragment exchange: 8 bpermutes -> one A-frag (verified mapping)
__device__ __forceinline__ short8 build_pa(int c0lo, int c0hi, int c1lo, int c1hi,
                                           int addrA, bool hi_m) {
  const int a0 = __builtin_amdgcn_ds_bpermute(addrA,      c0lo);
  const int b0 = __builtin_amdgcn_ds_bpermute(addrA,      c1lo);
  const int a1 = __builtin_amdgcn_ds_bpermute(addrA,      c0hi);
  const int b1 = __builtin_amdgcn_ds_bpermute(addrA,      c1hi);
  const int a2 = __builtin_amdgcn_ds_bpermute(addrA + 64, c0lo);
  const int b2 = __builtin_amdgcn_ds_bpermute(addrA + 64, c1lo);
  const int a3 = __builtin_amdgcn_ds_bpermute(addrA + 64, c0hi);
  const int b3 = __builtin_amdgcn_ds_bpermute(addrA + 64, c1hi);
  i32x4v pw;
  pw[0] = hi_m ? b0 : a0;
  pw[1] = hi_m ? b1 : a1;
  pw[2] = hi_m ? b2 : a2;
  pw[3] = hi_m ? b3 : a3;
  return __builtin_bit_cast(short8, pw);
}

// ============================================================================
// MFMA flash attention, split-S x3, QBLK=64.
// K and V^T staged in LDS via global_load_lds (dbuf, pre-swizzled src).
// Writes UNNORMALIZED O-partial (bf16) + per-(q,h) {m,l} (f32) for LSE merge.
// ============================================================================
__global__ __launch_bounds__(256) void attn_mfma(
    const unsigned short* __restrict__ Qbb,
    const unsigned short* __restrict__ Kbb,
    const unsigned short* __restrict__ VT,
    unsigned short* __restrict__ Op0,
    unsigned short* __restrict__ Op1,
    unsigned short* __restrict__ Op2,
    float* __restrict__ ml)
{
  __shared__ __align__(16) unsigned short Kl[2][64 * 64];   // [key][d], swz 16B
  __shared__ __align__(16) unsigned short Vl[2][64 * 64];   // [d][key], swz 16B

  const int sv = blockIdx.z;
  int bx = blockIdx.x, by = blockIdx.y;
  xcd_swz(bx, by);
  const int qb = bx, h = by;
  const int t = threadIdx.x, w = t >> 6, l = t & 63;
  const int lr = l & 15, lg = l >> 4;
  const int q0 = qb * 64;
  const int j0base = sv * (NTS_ * 64);
  unsigned short* Opart = (sv == 0) ? Op0 : (sv == 1) ? Op1 : Op2;

  short8 qa[2];
  {
    int qrow = q0 + w * 16 + lr; if (qrow >= S_) qrow = S_ - 1;
    const unsigned short* qp = Qbb + (size_t)qrow * DIM_ + h * 64 + lg * 8;
    qa[0] = *(const short8*)qp;
    qa[1] = *(const short8*)(qp + 32);
  }

  // staging constants: row within 64-row tile, pre-swizzled col (involution)
  const int srow = t >> 3;                 // +32 for second half
  const int sc0 = ((((t & 7) * 16) ^ ((srow        & 7) << 4)) >> 1);  // ushorts
  const int sc1 = ((((t & 7) * 16) ^ (((srow + 32) & 7) << 4)) >> 1);
  const unsigned short* vsrc0 = VT + (size_t)(h * 64 + srow)      * SP_ + sc0;
  const unsigned short* vsrc1 = VT + (size_t)(h * 64 + srow + 32) * SP_ + sc1;

  f32x4 oacc[4];
#pragma unroll
  for (int n = 0; n < 4; ++n) oacc[n] = (f32x4){0.f, 0.f, 0.f, 0.f};
  float m_run = -1e30f, l_run = 0.f;

  const int addrA = (lr + ((lg & 1) << 5)) << 2;
  const bool hi_m = (lg & 2) != 0;

  // ---- prologue: stage K+V tile 0 of this split ----
  {
    int k0 = j0base + srow;      if (k0 >= S_) k0 = S_ - 1;
    int k1 = j0base + srow + 32; if (k1 >= S_) k1 = S_ - 1;
    gload_lds16(Kbb + (size_t)k0 * DIM_ + h * 64 + sc0, (char*)Kl[0] + t * 16);
    gload_lds16(Kbb + (size_t)k1 * DIM_ + h * 64 + sc1, (char*)Kl[0] + 4096 + t * 16);
    gload_lds16(vsrc0 + j0base, (char*)Vl[0] + t * 16);
    gload_lds16(vsrc1 + j0base, (char*)Vl[0] + 4096 + t * 16);
  }
  __syncthreads();

  for (int jt = 0; jt < NTS_; ++jt) {
    const int j0 = j0base + jt * 64;
    const int cur = jt & 1;

    // ---- issue K+V prefetch for next tile (clamped re-read on last iter) --
    const int jn0 = (jt + 1 < NTS_) ? j0 + 64 : j0;
    {
      int k0 = jn0 + srow;      if (k0 >= S_) k0 = S_ - 1;
      int k1 = jn0 + srow + 32; if (k1 >= S_) k1 = S_ - 1;
      gload_lds16(Kbb + (size_t)k0 * DIM_ + h * 64 + sc0,
                  (char*)Kl[cur ^ 1] + t * 16);
      gload_lds16(Kbb + (size_t)k1 * DIM_ + h * 64 + sc1,
                  (char*)Kl[cur ^ 1] + 4096 + t * 16);
      gload_lds16(vsrc0 + jn0, (char*)Vl[cur ^ 1] + t * 16);
      gload_lds16(vsrc1 + jn0, (char*)Vl[cur ^ 1] + 4096 + t * 16);
    }

    // ---- S^T = K @ Q^T : lane holds S[key = m*16+lg*4+r][q = lr] ----
    f32x4 sacc[4];
#pragma unroll
    for (int m = 0; m < 4; ++m) sacc[m] = (f32x4){0.f, 0.f, 0.f, 0.f};
    __builtin_amdgcn_s_setprio(1);
#pragma unroll
    for (int m = 0; m < 4; ++m) {
#pragma unroll
      for (int ks = 0; ks < 2; ++ks) {
        const short8 kb = *(const short8*)((const char*)Kl[cur] + (m * 16 + lr) * 128 +
                              ((ks * 64 + lg * 16) ^ ((lr & 7) << 4)));
        sacc[m] = __builtin_amdgcn_mfma_f32_16x16x32_bf16(kb, qa[ks], sacc[m], 0, 0, 0);
      }
    }
    __builtin_amdgcn_s_setprio(0);

    if (j0 + 64 > S_) {
#pragma unroll
      for (int m = 0; m < 4; ++m)
#pragma unroll
        for (int r = 0; r < 4; ++r)
          if (j0 + m * 16 + lg * 4 + r >= S_) sacc[m][r] = -1e30f;
    }

    // ---- row max ----
    float mx = sacc[0][0];
#pragma unroll
    for (int m = 0; m < 4; ++m)
#pragma unroll
      for (int r = 0; r < 4; ++r) mx = fmaxf(mx, sacc[m][r]);
    mx = fmaxf(mx, __shfl_xor(mx, 16));
    mx = fmaxf(mx, __shfl_xor(mx, 32));

    // ---- defer-max rescale (exp2 domain, THR=8) ----
    if (!__all(mx <= m_run + 8.0f)) {
      const float mnew = fmaxf(m_run, mx);
      const float sc = exp2f(m_run - mnew);
      l_run *= sc;
      float scr[4];
#pragma unroll
      for (int r = 0; r < 4; ++r) scr[r] = __shfl(sc, (l & 48) | (lg * 4 + r));
#pragma unroll
      for (int n = 0; n < 4; ++n)
#pragma unroll
        for (int r = 0; r < 4; ++r) oacc[n][r] *= scr[r];
      m_run = mnew;
    }

    // ---- P = exp2(S - m), packed to bf16 pairs in-register ----
    float rs = 0.f;
    int c[4][2];
#pragma unroll
    for (int m = 0; m < 4; ++m) {
      const float p0 = exp2f(sacc[m][0] - m_run);
      const float p1 = exp2f(sacc[m][1] - m_run);
      const float p2 = exp2f(sacc[m][2] - m_run);
      const float p3 = exp2f(sacc[m][3] - m_run);
      rs += (p0 + p1) + (p2 + p3);
      asm("v_cvt_pk_bf16_f32 %0, %1, %2" : "=v"(c[m][0]) : "v"(p0), "v"(p1));
      asm("v_cvt_pk_bf16_f32 %0, %1, %2" : "=v"(c[m][1]) : "v"(p2), "v"(p3));
    }
    rs += __shfl_xor(rs, 16);
    rs += __shfl_xor(rs, 32);
    l_run += rs;

    // ---- P A-frags via bpermute, then O += P @ V (V^T from LDS) ----
    __builtin_amdgcn_s_setprio(1);
    {
      const short8 pa0 = build_pa(c[0][0], c[0][1], c[1][0], c[1][1], addrA, hi_m);
#pragma unroll
      for (int n = 0; n < 4; ++n) {
        const short8 vb = *(const short8*)((const char*)Vl[cur] + (n * 16 + lr) * 128 +
                              ((0 * 64 + lg * 16) ^ ((lr & 7) << 4)));
        oacc[n] = __builtin_amdgcn_mfma_f32_16x16x32_bf16(pa0, vb, oacc[n], 0, 0, 0);
      }
      const short8 pa1 = build_pa(c[2][0], c[2][1], c[3][0], c[3][1], addrA, hi_m);
#pragma unroll
      for (int n = 0; n < 4; ++n) {
        const short8 vb = *(const short8*)((const char*)Vl[cur] + (n * 16 + lr) * 128 +
                              ((1 * 64 + lg * 16) ^ ((lr & 7) << 4)));
        oacc[n] = __builtin_amdgcn_mfma_f32_16x16x32_bf16(pa1, vb, oacc[n], 0, 0, 0);
      }
    }
    __builtin_amdgcn_s_setprio(0);

    __syncthreads();     // drains K+V DMA; Kl/Vl[cur^1] ready for next iter
  }

  // ---- epilogue: store UNNORMALIZED partial + {m,l} ----
#pragma unroll
  for (int r = 0; r < 4; ++r) {
    const int row = q0 + w * 16 + lg * 4 + r;
    if (row >= S_) continue;
#pragma unroll
    for (int n = 0; n < 4; ++n)
      Opart[(size_t)row * DIM_ + h * 64 + n * 16 + lr] = f2b(oacc[n][r]);
  }
  if (l < 16) {                       // lg==0 lane holds (m,l) for q = lr
    const int row = q0 + w * 16 + lr;
    if (row < S_) {
      float2 v; v.x = m_run; v.y = l_run;
      *(float2*)(ml + ((size_t)(sv * S_ + row) * HEADS_ + h) * 2) = v;
    }
  }
}

// ============================================================================
// merge split-S x3 partials (LSE combine) + conv-branch add -> bf16
// fused tail range: out-proj weight f32 -> bf16 (x8 vectorized)
// ============================================================================
#define MERGE_N_ (S_ * DIM_ / 8)
#define CVT_N_   (DIM_ * DIM_ / 8)
__global__ void merge_k(const unsigned short* __restrict__ Op0,
                        const unsigned short* __restrict__ Op1,
                        const unsigned short* __restrict__ Op2,
                        const float* __restrict__ ml,
                        const unsigned short* __restrict__ y2b,
                        unsigned short* __restrict__ dst,
                        const float* __restrict__ ow,
                        unsigned short* __restrict__ owb)
{
  const int i = blockIdx.x * 256 + threadIdx.x;
  if (i < MERGE_N_) {
    const int e = i * 8;
    const int row = e / DIM_, col = e % DIM_;
    const int h = col >> 6;
    float mv[NS_], lv[NS_];
#pragma unroll
    for (int ss = 0; ss < NS_; ++ss) {
      const float* pp = ml + ((size_t)(ss * S_ + row) * HEADS_ + h) * 2;
      mv[ss] = pp[0]; lv[ss] = pp[1];
    }
    float M = mv[0];
#pragma unroll
    for (int ss = 1; ss < NS_; ++ss) M = fmaxf(M, mv[ss]);
    float wv[NS_], L = 0.f;
#pragma unroll
    for (int ss = 0; ss < NS_; ++ss) {
      wv[ss] = exp2f(mv[ss] - M);
      L = fmaf(wv[ss], lv[ss], L);
    }
    const float inv = 1.f / L;
    const short8 a = *(const short8*)(Op0 + e);
    const short8 b = *(const short8*)(Op1 + e);
    const short8 c2 = *(const short8*)(Op2 + e);
    const bool cadd = row >= T_;
    const unsigned short* yp = y2b + (size_t)(row - T_) * DIM_ + col;
    short8 o;
#pragma unroll
    for (int j = 0; j < 8; ++j) {
      float v = (wv[0] * b2f((unsigned short)a[j]) +
                 wv[1] * b2f((unsigned short)b[j]) +
                 wv[2] * b2f((unsigned short)c2[j])) * inv;
      if (cadd) v += b2f(yp[j]);
      o[j] = (short)f2b(v);
    }
    *(short8*)(dst + e) = o;
  } else if (i < MERGE_N_ + CVT_N_) {
    const int e = (i - MERGE_N_) * 8;
    const float4 v0 = *(const float4*)(ow + e);
    const float4 v1 = *(const float4*)(ow + e + 4);
    short8 o;
    o[0]=(short)f2b(v0.x); o[1]=(short)f2b(v0.y); o[2]=(short)f2b(v0.z); o[3]=(short)f2b(v0.w);
    o[4]=(short)f2b(v1.x); o[5]=(short)f2b(v1.y); o[6]=(short)f2b(v1.z); o[7]=(short)f2b(v1.w);
    *(short8*)(owb + e) = o;
  }
}

// ============================================================================
// fused input conversions (one launch)
// ============================================================================
#define U0_ 1228800
#define U1_ 3993600
#define U2_ 4427520
#define U3_ 5164800
#define U4_ 5902080
#define U5_ 5907840
__global__ void prep_all(const float* __restrict__ hid, const float* __restrict__ enc,
                         const float* __restrict__ w1, const float* __restrict__ w2,
                         const float* __restrict__ qw, const float* __restrict__ kw,
                         const float* __restrict__ vw, const float* __restrict__ qb2,
                         const float* __restrict__ kb2, const float* __restrict__ vb2,
                         unsigned short* __restrict__ hidpad, unsigned short* __restrict__ encb,
                         unsigned short* __restrict__ w1p, unsigned short* __restrict__ w2p,
                         unsigned short* __restrict__ wqkv, float* __restrict__ bqkv)
{
  const int i = blockIdx.x * 256 + threadIdx.x;
  if (i < U0_) {                                   // hidpad (zero-padded), x4
    const int e = i * 4;
    const int r = e / DIM_;
    ushort4v o = (ushort4v){0, 0, 0, 0};
    if (r >= 256 && r < 256 + SV_) {
      const float4 v = *(const float4*)(hid + e - 256 * DIM_);
      o[0] = f2b(v.x); o[1] = f2b(v.y); o[2] = f2b(v.z); o[3] = f2b(v.w);
    }
    *(ushort4v*)(hidpad + e) = o;
  } else if (i < U1_) {                            // fused QKV weights, x4
    const int e = (i - U0_) * 4;
    const int which = e / (DIM_ * DIM_);
    const int j = e - which * DIM_ * DIM_;
    const float* s = which == 0 ? qw : which == 1 ? kw : vw;
    const float4 v = *(const float4*)(s + j);
    ushort4v o = {f2b(v.x), f2b(v.y), f2b(v.z), f2b(v.w)};
    *(ushort4v*)(wqkv + e) = o;
  } else if (i < U2_) {                            // encoder bf16
    const int e = i - U1_;
    encb[e] = f2b(enc[e]);
  } else if (i < U3_) {                            // conv1 w permute
    const int e = i - U2_;
    const int oc = e / (DIM_ * 3), rem = e % (DIM_ * 3);
    const int ks = rem / DIM_, ic = rem % DIM_;
    w1p[e] = f2b(w1[(size_t)oc * DIM_ * 3 + ic * 3 + ks]);
  } else if (i < U4_) {                            // conv2 w permute
    const int e = i - U3_;
    const int oc = e / (RANK_ * 3), rem = e % (RANK_ * 3);
    const int ks = rem / RANK_, rc = rem % RANK_;
    w2p[e] = f2b(w2[(size_t)oc * RANK_ * 3 + rc * 3 + ks]);
  } else if (i < U5_) {                            // fused QKV bias (f32)
    const int e = i - U4_;
    const int which = e / DIM_, j = e % DIM_;
    bqkv[e] = which == 0 ? qb2[j] : which == 1 ? kb2[j] : vb2[j];
  }
}

// sum 12 split-K partials of y1^T [128][2048], GELU, write padded [2560][128]
__global__ void gelupad_k(const float* __restrict__ y1T, unsigned short* __restrict__ dst)
{
  int i = blockIdx.x * 256 + threadIdx.x;
  if (i >= 2560 * RANK_) return;
  int r = i / RANK_, rc = i % RANK_;
  unsigned short o = 0;
  if (r >= 256 && r < 256 + SV_) {
    int s = r - 256;
    float x = 0.f;
#pragma unroll
    for (int z = 0; z < 12; ++z)
      x += y1T[(size_t)z * RANK_ * SV_ + (size_t)rc * SV_ + s];
    o = f2b(0.5f * x * (1.f + erff(x * 0.70710678118654752f)));
  }
  dst[i] = o;
}

// ============================================================================
// LN over HD=64 + RoPE, vectorized: 8 lanes x short8 per row, 8 rows per wave.
// bf16 in place; Q branch scaled by log2(e)/8. RoPE pairs are in-register.
// ============================================================================
__global__ __launch_bounds__(256) void qknorm_rope(
    unsigned short* __restrict__ Qbb, unsigned short* __restrict__ Kbb,
    const float* __restrict__ nq_w, const float* __restrict__ nq_b,
    const float* __restrict__ nk_w, const float* __restrict__ nk_b,
    const float* __restrict__ cosT, const float* __restrict__ sinT)
{
  const int w = threadIdx.x >> 6, l = threadIdx.x & 63;
  const int g = l >> 3, e = l & 7;           // 8 row-groups x 8 dims-of-8
  const int idx = (blockIdx.x * 4 + w) * 8 + g;
  if (idx >= S_ * HEADS_) return;
  const int s = idx / HEADS_, h = idx % HEADS_;
  unsigned short* X = blockIdx.y ? Kbb : Qbb;
  const float* wt = blockIdx.y ? nk_w : nq_w;
  const float* bt = blockIdx.y ? nk_b : nq_b;
  const size_t off = (size_t)s * DIM_ + h * HD_ + e * 8;

  const short8 xv = *(const short8*)(X + off);
  float x[8];
#pragma unroll
  for (int j = 0; j < 8; ++j) x[j] = b2f((unsigned short)xv[j]);

  float sm = 0.f;
#pragma unroll
  for (int j = 0; j < 8; ++j) sm += x[j];
  sm += __shfl_xor(sm, 1); sm += __shfl_xor(sm, 2); sm += __shfl_xor(sm, 4);
  const float mean = sm * (1.f / 64.f);
  float vr = 0.f;
#pragma unroll
  for (int j = 0; j < 8; ++j) { const float d = x[j] - mean; vr += d * d; }
  vr += __shfl_xor(vr, 1); vr += __shfl_xor(vr, 2); vr += __shfl_xor(vr, 4);
  const float inv = rsqrtf(vr * (1.f / 64.f) + 1e-6f);

  const float4 w0 = *(const float4*)(wt + e * 8);
  const float4 w1 = *(const float4*)(wt + e * 8 + 4);
  const float4 b0 = *(const float4*)(bt + e * 8);
  const float4 b1 = *(const float4*)(bt + e * 8 + 4);
  const float wa[8] = {w0.x, w0.y, w0.z, w0.w, w1.x, w1.y, w1.z, w1.w};
  const float ba[8] = {b0.x, b0.y, b0.z, b0.w, b1.x, b1.y, b1.z, b1.w};
  float y[8];
#pragma unroll
  for (int j = 0; j < 8; ++j) y[j] = (x[j] - mean) * inv * wa[j] + ba[j];

  if (s >= T_) {
    const int sv2 = s - T_;
    const float4 c0 = *(const float4*)(cosT + (size_t)sv2 * HD_ + e * 8);
    const float4 c1 = *(const float4*)(cosT + (size_t)sv2 * HD_ + e * 8 + 4);
    const float4 s0 = *(const float4*)(sinT + (size_t)sv2 * HD_ + e * 8);
    const float4 s1 = *(const float4*)(sinT + (size_t)sv2 * HD_ + e * 8 + 4);
    const float cc[8] = {c0.x, c0.y, c0.z, c0.w, c1.x, c1.y, c1.z, c1.w};
    const float ssn[8] = {s0.x, s0.y, s0.z, s0.w, s1.x, s1.y, s1.z, s1.w};
#pragma unroll
    for (int j = 0; j < 8; j += 2) {
      const float a = y[j], bb = y[j + 1];
      y[j]     = a  * cc[j]     - bb * ssn[j];
      y[j + 1] = bb * cc[j + 1] + a  * ssn[j + 1];
    }
  }
  const float qs = blockIdx.y ? 1.f : 0.18033688011112042f;   // (1/8)*log2(e)
  short8 o;
#pragma unroll
  for (int j = 0; j < 8; ++j) o[j] = (short)f2b(y[j] * qs);
  *(short8*)(X + off) = o;
}

// ============================================================================
extern "C" void kernel_launch(void* const* d_in, const int* in_sizes, int n_in,
                              void* d_out, int out_size, void* d_ws, size_t ws_size,
                              hipStream_t stream)
{
  const float* hidden  = (const float*)d_in[0];
  const float* encoder = (const float*)d_in[1];
  const float* cosT    = (const float*)d_in[2];
  const float* sinT    = (const float*)d_in[3];
  const float* to_q_w  = (const float*)d_in[4];
  const float* to_q_b  = (const float*)d_in[5];
  const float* to_k_w  = (const float*)d_in[6];
  const float* to_k_b  = (const float*)d_in[7];
  const float* to_v_w  = (const float*)d_in[8];
  const float* to_v_b  = (const float*)d_in[9];
  const float* nq_w    = (const float*)d_in[10];
  const float* nq_b    = (const float*)d_in[11];
  const float* nk_w    = (const float*)d_in[12];
  const float* nk_b    = (const float*)d_in[13];
  const float* conv1_w = (const float*)d_in[14];
  const float* conv2_w = (const float*)d_in[15];
  const float* to_out_w = (const float*)d_in[16];
  const float* to_out_b = (const float*)d_in[17];
  float* out = (float*)d_out;

  // ---- workspace layout: ~83.2 MB total (>=85.58 MB proven available) ----
  char* p = (char*)d_ws;
  unsigned short* hidpad = (unsigned short*)p;  p += (size_t)2560 * DIM_ * 2;        // 9.83 MB (later Opart0)
  unsigned short* y2b    = (unsigned short*)p;  p += (size_t)SV_ * DIM_ * 2;         // 7.86 MB
  unsigned short* wqkv   = (unsigned short*)p;  p += (size_t)3 * DIM_ * DIM_ * 2;    // 22.12 MB (later owb + Opart2)
  unsigned short* w1p    = (unsigned short*)p;  p += (size_t)RANK_ * DIM_ * 3 * 2;   // 1.47 MB
  unsigned short* w2p    = (unsigned short*)p;  p += (size_t)DIM_ * RANK_ * 3 * 2;   // 1.47 MB
  unsigned short* QKbb   = (unsigned short*)p;  p += (size_t)2 * S_ * DIM_ * 2;      // 17.46 MB
  unsigned short* VbbT   = (unsigned short*)p;  p += (size_t)DIM_ * SP_ * 2;         // 8.85 MB
  unsigned short* encb   = (unsigned short*)p;  p += (size_t)T_ * DIM_ * 2;          // 0.87 MB
  float*          y1T    = (float*)p;           p += (size_t)12 * RANK_ * SV_ * 4;   // 12.58 MB (later Opart1+ml)
  unsigned short* gelup  = (unsigned short*)p;  p += (size_t)2560 * RANK_ * 2;       // 0.66 MB
  float*          bqkv   = (float*)p;           p += (size_t)3 * DIM_ * 4;           // 23 KB
  unsigned short* Qbb = QKbb;
  unsigned short* Kbb = QKbb + (size_t)S_ * DIM_;
  // split-S x3 partial buffers overlay dead regions:
  unsigned short* Op0 = hidpad;                            // 8.73 <= 9.83 MB
  unsigned short* Op1 = (unsigned short*)y1T;              // 8.73 MB
  float*          ml  = (float*)((char*)y1T + (size_t)S_ * DIM_ * 2);  // 1.64 MB (8.73+1.64 < 12.58)
  unsigned short* Op2 = wqkv + (size_t)DIM_ * DIM_;        // 8.73 <= 22.12-7.37 MB
  unsigned short* owb = wqkv;                              // out-w bf16, first 7.37 MB

  // ---- fused input conversions ----
  prep_all<<<(U5_ + 255) / 256, 256, 0, stream>>>(
      hidden, encoder, conv1_w, conv2_w, to_q_w, to_k_w, to_v_w,
      to_q_b, to_k_b, to_v_b, hidpad, encb, w1p, w2p, wqkv, bqkv);

  // ---- conv branch ----
  gemm_mfma<3, 0, 32><<<dim3(SV_ / BN, 1, 12), 256, 0, stream>>>(
      w1p, nullptr, hidpad, nullptr, y1T, nullptr, RANK_, SV_, 480, DIM_ * 3, DIM_, 1);
  gelupad_k<<<(2560 * RANK_ + 255) / 256, 256, 0, stream>>>(y1T, gelup);
  gemm_mfma<1, 1, 64><<<dim3(DIM_ / BN, SV_ / BM), 256, 0, stream>>>(
      gelup, nullptr, w2p, nullptr, y2b, nullptr, SV_, DIM_, RANK_ * 3, RANK_ * 3, RANK_ * 3, RANK_);

  // ---- fused QKV projection (bf16 out; V written transposed) ----
  const unsigned short* hid0 = hidpad + (size_t)256 * DIM_;
  gemm_mfma<2, 3, 64><<<dim3(3 * DIM_ / BN, (S_ + BM - 1) / BM), 256, 0, stream>>>(
      encb, hid0, wqkv, bqkv, QKbb, VbbT, S_, 3 * DIM_, DIM_, DIM_, DIM_, 1);

  // ---- LN + RoPE (bf16 in place on Q,K; Q scaled log2e/8) ----
  qknorm_rope<<<dim3((S_ * HEADS_ + 31) / 32, 2), 256, 0, stream>>>(
      Qbb, Kbb, nq_w, nq_b, nk_w, nk_b, cosT, sinT);

  // ---- MFMA flash attention, split-S x3 (partials + ml) ----
  attn_mfma<<<dim3((S_ + 63) / 64, HEADS_, NS_), 256, 0, stream>>>(
      Qbb, Kbb, VbbT, Op0, Op1, Op2, ml);

  // ---- LSE merge + conv-add -> Qbb; fused out-proj weight cvt -> owb ----
  merge_k<<<(MERGE_N_ + CVT_N_ + 255) / 256, 256, 0, stream>>>(
      Op0, Op1, Op2, ml, y2b, Qbb, to_out_w, owb);

  // ---- output projection -> d_out (fp32, tuple remap) ----
  gemm_mfma<0, 2, 64><<<dim3(DIM_ / BN, (S_ + BM - 1) / BM), 256, 0, stream>>>(
      Qbb, nullptr, owb, to_out_b, out, nullptr, S_, DIM_, DIM_, DIM_, DIM_, 1);
}